// Round 3
// baseline (1565.174 us; speedup 1.0000x reference)
//
#include <hip/hip_runtime.h>
#include <cstdint>
#include <cstddef>

// ---------------------------------------------------------------------------
// Mamba2 layer forward for B=4, L=2048, d_model=512, d_inner=1024, d_state=128,
// nheads=1, headdim=1024, d_conv=4, ngroups=1.
// Pipeline: cast -> GEMM1(bf16 MFMA) -> dt(f32) -> conv+silu -> chunked scan
//           (S1 local, S2 combine, S3 final+y) -> gate+RMSNorm -> GEMM2 -> out
// R1: scan split 4 lanes/p — REGRESSED: compiler kept st[32] in scratch
//     (VGPR_Count=36!), latency-bound, 915us.
// R2: state as 8 explicit f32x4 vars (no array => no scratch demotion),
//     cstate layout (b,c,p,n) for dwordx4 save/restore, launch_bounds(256,2).
// ---------------------------------------------------------------------------

typedef __bf16 bf16_t;
typedef __bf16 bf16x8 __attribute__((ext_vector_type(8)));
typedef __bf16 bf16x4 __attribute__((ext_vector_type(4)));
typedef float  f32x4  __attribute__((ext_vector_type(4)));

#define BATCH   4
#define SEQLEN  2048
#define MROWS   8192          // B*L
#define DMODEL  512
#define DINNER  1024
#define DSTATE  128
#define NZX     2304          // z(1024) + xBC(1280); dt col handled separately
#define NCONV   1280
#define CHUNK   128           // scan chunk length
#define NCHUNK  16            // SEQLEN / CHUNK

__device__ __forceinline__ float siluf(float x) { return x / (1.f + __expf(-x)); }

// ---------------------------------------------------------------------------
// f32 -> bf16 cast (vectorized), n4 = number of float4 groups
// ---------------------------------------------------------------------------
__global__ __launch_bounds__(256) void cast_bf16_kernel(
    const float* __restrict__ in, bf16_t* __restrict__ out, int n4)
{
    int i = blockIdx.x * 256 + threadIdx.x;
    if (i < n4) {
        float4 v = reinterpret_cast<const float4*>(in)[i];
        bf16x4 o;
        o[0] = (bf16_t)v.x; o[1] = (bf16_t)v.y; o[2] = (bf16_t)v.z; o[3] = (bf16_t)v.w;
        reinterpret_cast<bf16x4*>(out)[i] = o;
    }
}

// ---------------------------------------------------------------------------
// bf16 MFMA GEMM: C[M,N] = A[M,K] * B[N,K]^T   (both row-major, K contiguous)
// 128x128 tile, BK=64, 256 threads (4 waves in 2x2 of 64x64), 16x16x32 mfma.
// ---------------------------------------------------------------------------
template <typename OutT>
__global__ __launch_bounds__(256) void gemm_bf16_kernel(
    const bf16_t* __restrict__ A, const bf16_t* __restrict__ B,
    OutT* __restrict__ C, int M, int N, int K)
{
    constexpr int LDT = 72;   // 64 + 8 pad (keeps 16B alignment, spreads banks)
    __shared__ __align__(16) bf16_t As[128 * LDT];
    __shared__ __align__(16) bf16_t Bs[128 * LDT];

    const int bn = blockIdx.x, bm = blockIdx.y;
    const int tid  = threadIdx.x;
    const int wave = tid >> 6, lane = tid & 63;
    const int lr = lane & 15, q = lane >> 4;
    const int wm = (wave & 1) * 64, wn = (wave >> 1) * 64;

    f32x4 acc[4][4];
    #pragma unroll
    for (int i = 0; i < 4; ++i)
        #pragma unroll
        for (int j = 0; j < 4; ++j)
            acc[i][j] = (f32x4){0.f, 0.f, 0.f, 0.f};

    const int row_a0 = bm * 128, row_b0 = bn * 128;
    const int srow = tid >> 3, skc = tid & 7;   // staging: 16B chunk per thread

    for (int kt = 0; kt < K; kt += 64) {
        #pragma unroll
        for (int i = 0; i < 4; ++i) {
            int row = srow + i * 32;
            bf16x8 av = *reinterpret_cast<const bf16x8*>(
                &A[(size_t)(row_a0 + row) * K + kt + skc * 8]);
            *reinterpret_cast<bf16x8*>(&As[row * LDT + skc * 8]) = av;
            bf16x8 bv = *reinterpret_cast<const bf16x8*>(
                &B[(size_t)(row_b0 + row) * K + kt + skc * 8]);
            *reinterpret_cast<bf16x8*>(&Bs[row * LDT + skc * 8]) = bv;
        }
        __syncthreads();
        #pragma unroll
        for (int k0 = 0; k0 < 64; k0 += 32) {
            bf16x8 af[4], bfr[4];
            #pragma unroll
            for (int mi = 0; mi < 4; ++mi)
                af[mi] = *reinterpret_cast<const bf16x8*>(
                    &As[(wm + mi * 16 + lr) * LDT + k0 + q * 8]);
            #pragma unroll
            for (int ni = 0; ni < 4; ++ni)
                bfr[ni] = *reinterpret_cast<const bf16x8*>(
                    &Bs[(wn + ni * 16 + lr) * LDT + k0 + q * 8]);
            #pragma unroll
            for (int mi = 0; mi < 4; ++mi)
                #pragma unroll
                for (int ni = 0; ni < 4; ++ni)
                    acc[mi][ni] = __builtin_amdgcn_mfma_f32_16x16x32_bf16(
                        af[mi], bfr[ni], acc[mi][ni], 0, 0, 0);
        }
        __syncthreads();
    }

    // C/D layout (verified m89/m91): col = lane&15, row = (lane>>4)*4 + reg
    #pragma unroll
    for (int mi = 0; mi < 4; ++mi)
        #pragma unroll
        for (int ni = 0; ni < 4; ++ni)
            #pragma unroll
            for (int ri = 0; ri < 4; ++ri) {
                int row = row_a0 + wm + mi * 16 + q * 4 + ri;
                int col = row_b0 + wn + ni * 16 + lr;
                C[(size_t)row * N + col] = (OutT)acc[mi][ni][ri];
            }
}

// ---------------------------------------------------------------------------
// dt column: dt_raw[r] = dot(x[r,:], W_in[2304,:]) ; dt = softplus(dt_raw+bias)
// dA = exp(dt * A), A = -exp(A_log). One wave per row, fp32 exact.
// ---------------------------------------------------------------------------
__global__ __launch_bounds__(256) void dt_kernel(
    const float* __restrict__ x, const float* __restrict__ W_in,
    const float* __restrict__ dt_bias, const float* __restrict__ A_log,
    float* __restrict__ dtv, float* __restrict__ dAv)
{
    int wave = threadIdx.x >> 6, lane = threadIdx.x & 63;
    int r = blockIdx.x * 4 + wave;
    const float* xr = x + (size_t)r * DMODEL + lane * 8;
    const float* wr = W_in + (size_t)NZX * DMODEL + lane * 8;
    float4 a0 = *reinterpret_cast<const float4*>(xr);
    float4 a1 = *reinterpret_cast<const float4*>(xr + 4);
    float4 b0 = *reinterpret_cast<const float4*>(wr);
    float4 b1 = *reinterpret_cast<const float4*>(wr + 4);
    float s = a0.x * b0.x + a0.y * b0.y + a0.z * b0.z + a0.w * b0.w
            + a1.x * b1.x + a1.y * b1.y + a1.z * b1.z + a1.w * b1.w;
    #pragma unroll
    for (int m = 32; m >= 1; m >>= 1) s += __shfl_xor(s, m);
    if (lane == 0) {
        float t  = s + dt_bias[0];
        float sp = (t > 20.f) ? t : log1pf(expf(t));
        float A  = -expf(A_log[0]);
        dtv[r] = sp;
        dAv[r] = expf(sp * A);
    }
}

// ---------------------------------------------------------------------------
// Causal depthwise conv1d (width 4) + bias + silu over 1280 channels.
// Input: zxbcdt bf16 (stride NZX), channels at col offset 1024. Output f32.
// ---------------------------------------------------------------------------
__global__ __launch_bounds__(256) void conv_kernel(
    const bf16_t* __restrict__ zx, const float* __restrict__ cw,
    const float* __restrict__ cb, float* __restrict__ xconv)
{
    int flat = blockIdx.x * 256 + threadIdx.x;   // MROWS * 320
    int c4 = flat % (NCONV / 4);
    int r  = flat / (NCONV / 4);
    int l  = r & (SEQLEN - 1);
    int ch = c4 * 4;

    float4 w0 = *reinterpret_cast<const float4*>(cw + (size_t)(ch + 0) * 4);
    float4 w1 = *reinterpret_cast<const float4*>(cw + (size_t)(ch + 1) * 4);
    float4 w2 = *reinterpret_cast<const float4*>(cw + (size_t)(ch + 2) * 4);
    float4 w3 = *reinterpret_cast<const float4*>(cw + (size_t)(ch + 3) * 4);
    float w0a[4] = {w0.x, w0.y, w0.z, w0.w};
    float w1a[4] = {w1.x, w1.y, w1.z, w1.w};
    float w2a[4] = {w2.x, w2.y, w2.z, w2.w};
    float w3a[4] = {w3.x, w3.y, w3.z, w3.w};

    float4 bias = *reinterpret_cast<const float4*>(cb + ch);
    float a0 = bias.x, a1 = bias.y, a2 = bias.z, a3 = bias.w;

    #pragma unroll
    for (int k = 0; k < 4; ++k) {
        if (l + k >= 3) {
            bf16x4 v = *reinterpret_cast<const bf16x4*>(
                zx + (size_t)(r + k - 3) * NZX + DINNER + ch);
            a0 += w0a[k] * (float)v[0];
            a1 += w1a[k] * (float)v[1];
            a2 += w2a[k] * (float)v[2];
            a3 += w3a[k] * (float)v[3];
        }
    }
    float4 out;
    out.x = siluf(a0); out.y = siluf(a1); out.z = siluf(a2); out.w = siluf(a3);
    *reinterpret_cast<float4*>(xconv + (size_t)r * NCONV + ch) = out;
}

// ---------------------------------------------------------------------------
// Chunk decay products: chp[b*16+c] = prod_{t in chunk} dA
// ---------------------------------------------------------------------------
__global__ void chunk_prod_kernel(const float* __restrict__ dAv, float* __restrict__ chp)
{
    int t = threadIdx.x;          // 64 = B * NCHUNK
    int b = t >> 4, c = t & 15;
    float v = 1.f;
    for (int i = 0; i < CHUNK; ++i) v *= dAv[b * SEQLEN + c * CHUNK + i];
    chp[t] = v;
}

// ---------------------------------------------------------------------------
// S1: per-chunk local state from zero.
// Thread owns (p, n-quarter); state = 8 explicit f32x4 (register-resident).
// cstate layout: (b, c, p, n) -> offset ((b*16+c)<<17) + p*128 + n
// ---------------------------------------------------------------------------
__global__ __launch_bounds__(256, 2) void scan_local_kernel(
    const float* __restrict__ xconv, const float* __restrict__ dAv,
    const float* __restrict__ dtv, float* __restrict__ cstate)
{
    int blk = blockIdx.x;               // B * NCHUNK * 16 = 1024
    int b  = blk >> 8;
    int c  = (blk >> 4) & 15;
    int pg = blk & 15;
    int tid = threadIdx.x;
    int pp = tid >> 2;                  // 0..63
    int nq = tid & 3;                   // n-quarter
    int p  = pg * 64 + pp;
    int n0 = nq * 32;

    f32x4 s0 = 0.f, s1 = 0.f, s2 = 0.f, s3 = 0.f;
    f32x4 s4 = 0.f, s5 = 0.f, s6 = 0.f, s7 = 0.f;

    int r0 = b * SEQLEN + c * CHUNK;
    const float* xc = xconv + (size_t)r0 * NCONV;
    for (int tl = 0; tl < CHUNK; ++tl) {
        float dA   = dAv[r0 + tl];
        float coef = dtv[r0 + tl] * xc[p];
        const f32x4* Bp = reinterpret_cast<const f32x4*>(xc + DINNER + n0);
        f32x4 b0 = Bp[0], b1 = Bp[1], b2 = Bp[2], b3 = Bp[3];
        f32x4 b4 = Bp[4], b5 = Bp[5], b6 = Bp[6], b7 = Bp[7];
        s0 = s0 * dA + b0 * coef;  s1 = s1 * dA + b1 * coef;
        s2 = s2 * dA + b2 * coef;  s3 = s3 * dA + b3 * coef;
        s4 = s4 * dA + b4 * coef;  s5 = s5 * dA + b5 * coef;
        s6 = s6 * dA + b6 * coef;  s7 = s7 * dA + b7 * coef;
        xc += NCONV;
    }
    f32x4* outp = reinterpret_cast<f32x4*>(
        cstate + (((size_t)(b * NCHUNK + c)) << 17) + (size_t)p * DSTATE + n0);
    outp[0] = s0; outp[1] = s1; outp[2] = s2; outp[3] = s3;
    outp[4] = s4; outp[5] = s5; outp[6] = s6; outp[7] = s7;
}

// ---------------------------------------------------------------------------
// S2: sequential combine across chunks; converts local final states into
// chunk-initial states (in place).  Element-indexed, layout-agnostic.
// ---------------------------------------------------------------------------
__global__ __launch_bounds__(256) void scan_combine_kernel(
    float* __restrict__ cstate, const float* __restrict__ chp)
{
    int idx = blockIdx.x * 256 + threadIdx.x;   // B * 131072
    int b   = idx >> 17;
    int np  = idx & 131071;
    float v = 0.f;
    for (int c = 0; c < NCHUNK; ++c) {
        size_t off = ((size_t)(b * NCHUNK + c) << 17) + np;
        float tmp = cstate[off];
        cstate[off] = v;
        v = chp[b * NCHUNK + c] * v + tmp;
    }
}

// ---------------------------------------------------------------------------
// S3: replay chunk from its initial state, emit y[r,p] = state . C_t + Dp*x
// Same 4-lane split; state in 8 explicit f32x4; y reduced via 2x shfl_xor.
// ---------------------------------------------------------------------------
__global__ __launch_bounds__(256, 2) void scan_final_kernel(
    const float* __restrict__ xconv, const float* __restrict__ cstate,
    const float* __restrict__ dAv, const float* __restrict__ dtv,
    const float* __restrict__ Dp, float* __restrict__ yf)
{
    int blk = blockIdx.x;               // B * NCHUNK * 16 = 1024
    int b  = blk >> 8;
    int c  = (blk >> 4) & 15;
    int pg = blk & 15;
    int tid = threadIdx.x;
    int pp = tid >> 2;
    int nq = tid & 3;
    int p  = pg * 64 + pp;
    int n0 = nq * 32;

    const f32x4* inp = reinterpret_cast<const f32x4*>(
        cstate + (((size_t)(b * NCHUNK + c)) << 17) + (size_t)p * DSTATE + n0);
    f32x4 s0 = inp[0], s1 = inp[1], s2 = inp[2], s3 = inp[3];
    f32x4 s4 = inp[4], s5 = inp[5], s6 = inp[6], s7 = inp[7];

    float D0 = Dp[0];
    int r0 = b * SEQLEN + c * CHUNK;
    const float* xc = xconv + (size_t)r0 * NCONV;
    for (int tl = 0; tl < CHUNK; ++tl) {
        float dA   = dAv[r0 + tl];
        float xv   = xc[p];
        float coef = dtv[r0 + tl] * xv;
        const f32x4* Bp = reinterpret_cast<const f32x4*>(xc + DINNER + n0);
        const f32x4* Cp = reinterpret_cast<const f32x4*>(xc + DINNER + DSTATE + n0);
        f32x4 b0 = Bp[0], b1 = Bp[1], b2 = Bp[2], b3 = Bp[3];
        f32x4 c0 = Cp[0], c1 = Cp[1], c2 = Cp[2], c3 = Cp[3];
        s0 = s0 * dA + b0 * coef;  s1 = s1 * dA + b1 * coef;
        s2 = s2 * dA + b2 * coef;  s3 = s3 * dA + b3 * coef;
        f32x4 y4 = s0 * c0;
        y4 += s1 * c1; y4 += s2 * c2; y4 += s3 * c3;
        f32x4 b4 = Bp[4], b5 = Bp[5], b6 = Bp[6], b7 = Bp[7];
        f32x4 c4 = Cp[4], c5 = Cp[5], c6 = Cp[6], c7 = Cp[7];
        s4 = s4 * dA + b4 * coef;  s5 = s5 * dA + b5 * coef;
        s6 = s6 * dA + b6 * coef;  s7 = s7 * dA + b7 * coef;
        y4 += s4 * c4; y4 += s5 * c5; y4 += s6 * c6; y4 += s7 * c7;
        float y = y4[0] + y4[1] + y4[2] + y4[3];
        y += __shfl_xor(y, 1);
        y += __shfl_xor(y, 2);
        if (nq == 0)
            yf[(size_t)(r0 + tl) * DINNER + p] = y + D0 * xv;
        xc += NCONV;
    }
}

// ---------------------------------------------------------------------------
// Gate + RMSNorm: g = y*silu(z); g *= rsqrt(mean(g^2)+eps)*norm_w -> bf16
// One block (256 thr) per row; each thread 4 elements.
// ---------------------------------------------------------------------------
__global__ __launch_bounds__(256) void gate_norm_kernel(
    const float* __restrict__ yf, const bf16_t* __restrict__ zx,
    const float* __restrict__ norm_w, bf16_t* __restrict__ yb)
{
    __shared__ float red[4];
    int r = blockIdx.x, tid = threadIdx.x;
    int p = tid * 4;
    float4 y = *reinterpret_cast<const float4*>(yf + (size_t)r * DINNER + p);
    bf16x4 zv = *reinterpret_cast<const bf16x4*>(zx + (size_t)r * NZX + p);
    float z0 = (float)zv[0], z1 = (float)zv[1], z2 = (float)zv[2], z3 = (float)zv[3];
    float g0 = y.x * siluf(z0);
    float g1 = y.y * siluf(z1);
    float g2 = y.z * siluf(z2);
    float g3 = y.w * siluf(z3);
    float ss = g0 * g0 + g1 * g1 + g2 * g2 + g3 * g3;
    #pragma unroll
    for (int m = 32; m >= 1; m >>= 1) ss += __shfl_xor(ss, m);
    if ((tid & 63) == 0) red[tid >> 6] = ss;
    __syncthreads();
    float tot = red[0] + red[1] + red[2] + red[3];
    float scale = rsqrtf(tot * (1.f / 1024.f) + 1e-5f);
    float4 nw = *reinterpret_cast<const float4*>(norm_w + p);
    bf16x4 o;
    o[0] = (bf16_t)(g0 * scale * nw.x);
    o[1] = (bf16_t)(g1 * scale * nw.y);
    o[2] = (bf16_t)(g2 * scale * nw.z);
    o[3] = (bf16_t)(g3 * scale * nw.w);
    *reinterpret_cast<bf16x4*>(yb + (size_t)r * DINNER + p) = o;
}

// ---------------------------------------------------------------------------
// rnn_state passthrough into the output tail
// ---------------------------------------------------------------------------
__global__ __launch_bounds__(256) void copy_f32_kernel(
    const float* __restrict__ in, float* __restrict__ out, int n)
{
    int i = blockIdx.x * 256 + threadIdx.x;
    if (i < n) out[i] = in[i];
}

// ---------------------------------------------------------------------------
extern "C" void kernel_launch(void* const* d_in, const int* in_sizes, int n_in,
                              void* d_out, int out_size, void* d_ws, size_t ws_size,
                              hipStream_t stream)
{
    const float* x        = (const float*)d_in[0];
    const float* rnn      = (const float*)d_in[1];
    const float* W_in     = (const float*)d_in[2];
    const float* conv_w   = (const float*)d_in[3];
    const float* conv_b   = (const float*)d_in[4];
    const float* dt_bias  = (const float*)d_in[5];
    const float* A_log    = (const float*)d_in[6];
    const float* Dp       = (const float*)d_in[7];
    const float* norm_w   = (const float*)d_in[8];
    const float* W_out    = (const float*)d_in[9];
    float* out = (float*)d_out;

    // workspace carve (all sizes multiples of 256B)
    char* ws = (char*)d_ws;
    bf16_t* xb     = (bf16_t*)(ws + 0);                       //  8,388,608
    bf16_t* winb   = (bf16_t*)(ws + 8388608);                 //  2,360,320
    bf16_t* woutb  = (bf16_t*)(ws + 10748928);                //  1,048,576
    bf16_t* zx     = (bf16_t*)(ws + 11797504);                // 37,748,736
    float*  dtv    = (float*) (ws + 49546240);                //     32,768
    float*  dAv    = (float*) (ws + 49579008);                //     32,768
    float*  chp    = (float*) (ws + 49611776);                //        256
    float*  xconv  = (float*) (ws + 49612032);                // 41,943,040
    float*  cstate = (float*) (ws + 91555072);                // 33,554,432
    float*  yf     = (float*) (ws + 125109504);               // 33,554,432
    bf16_t* yb     = (bf16_t*)(ws + 158663936);               // 16,777,216
    // total 175,441,152 bytes

    // 1) casts to bf16
    cast_bf16_kernel<<<(MROWS * DMODEL / 4 + 255) / 256, 256, 0, stream>>>(x, xb, MROWS * DMODEL / 4);
    cast_bf16_kernel<<<(2305 * DMODEL / 4 + 255) / 256, 256, 0, stream>>>(W_in, winb, 2305 * DMODEL / 4);
    cast_bf16_kernel<<<(DMODEL * DINNER / 4 + 255) / 256, 256, 0, stream>>>(W_out, woutb, DMODEL * DINNER / 4);

    // 2) dt column (fp32 exact) -> dtv, dAv ; chunk decay products
    dt_kernel<<<MROWS / 4, 256, 0, stream>>>(x, W_in, dt_bias, A_log, dtv, dAv);
    chunk_prod_kernel<<<1, 64, 0, stream>>>(dAv, chp);

    // 3) GEMM1: zx[8192,2304] = xb * winb^T (bf16 out)
    gemm_bf16_kernel<bf16_t><<<dim3(NZX / 128, MROWS / 128), 256, 0, stream>>>(
        xb, winb, zx, MROWS, NZX, DMODEL);

    // 4) conv + bias + silu -> xconv f32 (1280 ch)
    conv_kernel<<<MROWS * (NCONV / 4) / 256, 256, 0, stream>>>(zx, conv_w, conv_b, xconv);

    // 5) chunked scan
    scan_local_kernel<<<BATCH * NCHUNK * 16, 256, 0, stream>>>(xconv, dAv, dtv, cstate);
    scan_combine_kernel<<<BATCH * 131072 / 256, 256, 0, stream>>>(cstate, chp);
    scan_final_kernel<<<BATCH * NCHUNK * 16, 256, 0, stream>>>(xconv, cstate, dAv, dtv, Dp, yf);

    // 6) gate + RMSNorm -> yb bf16
    gate_norm_kernel<<<MROWS, 256, 0, stream>>>(yf, zx, norm_w, yb);

    // 7) GEMM2: out[8192,512] = yb * woutb^T (f32 out, directly into d_out)
    gemm_bf16_kernel<float><<<dim3(DMODEL / 128, MROWS / 128), 256, 0, stream>>>(
        yb, woutb, out, MROWS, DMODEL, DINNER);

    // 8) rnn_state passthrough
    copy_f32_kernel<<<(BATCH * DMODEL + 255) / 256, 256, 0, stream>>>(
        rnn, out + (size_t)MROWS * DMODEL, BATCH * DMODEL);
}

// Round 4
// 609.410 us; speedup vs baseline: 2.5683x; 2.5683x over previous
//
#include <hip/hip_runtime.h>
#include <cstdint>
#include <cstddef>

// ---------------------------------------------------------------------------
// Mamba2 layer forward for B=4, L=2048, d_model=512, d_inner=1024, d_state=128,
// nheads=1, headdim=1024, d_conv=4, ngroups=1.
// Pipeline: cast -> GEMM1(bf16 MFMA) -> dt(f32) -> conv+silu -> chunked scan
//           (S1 local, S2 combine, S3 final+y) -> gate+RMSNorm -> GEMM2 -> out
// R1: scan split 4 lanes/p — REGRESSED: st[32] in scratch (VGPR=36), 915us.
// R2: 8 named f32x4 state — NEUTRAL: scheduler still targets 8 waves/EU
//     (<=64 VGPR), serialized loads (VGPR=48, VALUBusy 6%).
// R3: amdgpu_waves_per_eu(2,4) + 2p x 16n mapping (9 loads/iter not 17) +
//     dA/dt in LDS + explicit next-iter prefetch; parallel chunk_prod.
// ---------------------------------------------------------------------------

typedef __bf16 bf16_t;
typedef __bf16 bf16x8 __attribute__((ext_vector_type(8)));
typedef __bf16 bf16x4 __attribute__((ext_vector_type(4)));
typedef float  f32x4  __attribute__((ext_vector_type(4)));

#define BATCH   4
#define SEQLEN  2048
#define MROWS   8192          // B*L
#define DMODEL  512
#define DINNER  1024
#define DSTATE  128
#define NZX     2304          // z(1024) + xBC(1280); dt col handled separately
#define NCONV   1280
#define CHUNK   128           // scan chunk length
#define NCHUNK  16            // SEQLEN / CHUNK

__device__ __forceinline__ float siluf(float x) { return x / (1.f + __expf(-x)); }

// ---------------------------------------------------------------------------
// f32 -> bf16 cast (vectorized), n4 = number of float4 groups
// ---------------------------------------------------------------------------
__global__ __launch_bounds__(256) void cast_bf16_kernel(
    const float* __restrict__ in, bf16_t* __restrict__ out, int n4)
{
    int i = blockIdx.x * 256 + threadIdx.x;
    if (i < n4) {
        float4 v = reinterpret_cast<const float4*>(in)[i];
        bf16x4 o;
        o[0] = (bf16_t)v.x; o[1] = (bf16_t)v.y; o[2] = (bf16_t)v.z; o[3] = (bf16_t)v.w;
        reinterpret_cast<bf16x4*>(out)[i] = o;
    }
}

// ---------------------------------------------------------------------------
// bf16 MFMA GEMM: C[M,N] = A[M,K] * B[N,K]^T   (both row-major, K contiguous)
// 128x128 tile, BK=64, 256 threads (4 waves in 2x2 of 64x64), 16x16x32 mfma.
// ---------------------------------------------------------------------------
template <typename OutT>
__global__ __launch_bounds__(256) void gemm_bf16_kernel(
    const bf16_t* __restrict__ A, const bf16_t* __restrict__ B,
    OutT* __restrict__ C, int M, int N, int K)
{
    constexpr int LDT = 72;   // 64 + 8 pad (keeps 16B alignment, spreads banks)
    __shared__ __align__(16) bf16_t As[128 * LDT];
    __shared__ __align__(16) bf16_t Bs[128 * LDT];

    const int bn = blockIdx.x, bm = blockIdx.y;
    const int tid  = threadIdx.x;
    const int wave = tid >> 6, lane = tid & 63;
    const int lr = lane & 15, q = lane >> 4;
    const int wm = (wave & 1) * 64, wn = (wave >> 1) * 64;

    f32x4 acc[4][4];
    #pragma unroll
    for (int i = 0; i < 4; ++i)
        #pragma unroll
        for (int j = 0; j < 4; ++j)
            acc[i][j] = (f32x4){0.f, 0.f, 0.f, 0.f};

    const int row_a0 = bm * 128, row_b0 = bn * 128;
    const int srow = tid >> 3, skc = tid & 7;   // staging: 16B chunk per thread

    for (int kt = 0; kt < K; kt += 64) {
        #pragma unroll
        for (int i = 0; i < 4; ++i) {
            int row = srow + i * 32;
            bf16x8 av = *reinterpret_cast<const bf16x8*>(
                &A[(size_t)(row_a0 + row) * K + kt + skc * 8]);
            *reinterpret_cast<bf16x8*>(&As[row * LDT + skc * 8]) = av;
            bf16x8 bv = *reinterpret_cast<const bf16x8*>(
                &B[(size_t)(row_b0 + row) * K + kt + skc * 8]);
            *reinterpret_cast<bf16x8*>(&Bs[row * LDT + skc * 8]) = bv;
        }
        __syncthreads();
        #pragma unroll
        for (int k0 = 0; k0 < 64; k0 += 32) {
            bf16x8 af[4], bfr[4];
            #pragma unroll
            for (int mi = 0; mi < 4; ++mi)
                af[mi] = *reinterpret_cast<const bf16x8*>(
                    &As[(wm + mi * 16 + lr) * LDT + k0 + q * 8]);
            #pragma unroll
            for (int ni = 0; ni < 4; ++ni)
                bfr[ni] = *reinterpret_cast<const bf16x8*>(
                    &Bs[(wn + ni * 16 + lr) * LDT + k0 + q * 8]);
            #pragma unroll
            for (int mi = 0; mi < 4; ++mi)
                #pragma unroll
                for (int ni = 0; ni < 4; ++ni)
                    acc[mi][ni] = __builtin_amdgcn_mfma_f32_16x16x32_bf16(
                        af[mi], bfr[ni], acc[mi][ni], 0, 0, 0);
        }
        __syncthreads();
    }

    // C/D layout (verified m89/m91): col = lane&15, row = (lane>>4)*4 + reg
    #pragma unroll
    for (int mi = 0; mi < 4; ++mi)
        #pragma unroll
        for (int ni = 0; ni < 4; ++ni)
            #pragma unroll
            for (int ri = 0; ri < 4; ++ri) {
                int row = row_a0 + wm + mi * 16 + q * 4 + ri;
                int col = row_b0 + wn + ni * 16 + lr;
                C[(size_t)row * N + col] = (OutT)acc[mi][ni][ri];
            }
}

// ---------------------------------------------------------------------------
// dt column: dt_raw[r] = dot(x[r,:], W_in[2304,:]) ; dt = softplus(dt_raw+bias)
// dA = exp(dt * A), A = -exp(A_log). One wave per row, fp32 exact.
// ---------------------------------------------------------------------------
__global__ __launch_bounds__(256) void dt_kernel(
    const float* __restrict__ x, const float* __restrict__ W_in,
    const float* __restrict__ dt_bias, const float* __restrict__ A_log,
    float* __restrict__ dtv, float* __restrict__ dAv)
{
    int wave = threadIdx.x >> 6, lane = threadIdx.x & 63;
    int r = blockIdx.x * 4 + wave;
    const float* xr = x + (size_t)r * DMODEL + lane * 8;
    const float* wr = W_in + (size_t)NZX * DMODEL + lane * 8;
    float4 a0 = *reinterpret_cast<const float4*>(xr);
    float4 a1 = *reinterpret_cast<const float4*>(xr + 4);
    float4 b0 = *reinterpret_cast<const float4*>(wr);
    float4 b1 = *reinterpret_cast<const float4*>(wr + 4);
    float s = a0.x * b0.x + a0.y * b0.y + a0.z * b0.z + a0.w * b0.w
            + a1.x * b1.x + a1.y * b1.y + a1.z * b1.z + a1.w * b1.w;
    #pragma unroll
    for (int m = 32; m >= 1; m >>= 1) s += __shfl_xor(s, m);
    if (lane == 0) {
        float t  = s + dt_bias[0];
        float sp = (t > 20.f) ? t : log1pf(expf(t));
        float A  = -expf(A_log[0]);
        dtv[r] = sp;
        dAv[r] = expf(sp * A);
    }
}

// ---------------------------------------------------------------------------
// Causal depthwise conv1d (width 4) + bias + silu over 1280 channels.
// Input: zxbcdt bf16 (stride NZX), channels at col offset 1024. Output f32.
// ---------------------------------------------------------------------------
__global__ __launch_bounds__(256) void conv_kernel(
    const bf16_t* __restrict__ zx, const float* __restrict__ cw,
    const float* __restrict__ cb, float* __restrict__ xconv)
{
    int flat = blockIdx.x * 256 + threadIdx.x;   // MROWS * 320
    int c4 = flat % (NCONV / 4);
    int r  = flat / (NCONV / 4);
    int l  = r & (SEQLEN - 1);
    int ch = c4 * 4;

    float4 w0 = *reinterpret_cast<const float4*>(cw + (size_t)(ch + 0) * 4);
    float4 w1 = *reinterpret_cast<const float4*>(cw + (size_t)(ch + 1) * 4);
    float4 w2 = *reinterpret_cast<const float4*>(cw + (size_t)(ch + 2) * 4);
    float4 w3 = *reinterpret_cast<const float4*>(cw + (size_t)(ch + 3) * 4);
    float w0a[4] = {w0.x, w0.y, w0.z, w0.w};
    float w1a[4] = {w1.x, w1.y, w1.z, w1.w};
    float w2a[4] = {w2.x, w2.y, w2.z, w2.w};
    float w3a[4] = {w3.x, w3.y, w3.z, w3.w};

    float4 bias = *reinterpret_cast<const float4*>(cb + ch);
    float a0 = bias.x, a1 = bias.y, a2 = bias.z, a3 = bias.w;

    #pragma unroll
    for (int k = 0; k < 4; ++k) {
        if (l + k >= 3) {
            bf16x4 v = *reinterpret_cast<const bf16x4*>(
                zx + (size_t)(r + k - 3) * NZX + DINNER + ch);
            a0 += w0a[k] * (float)v[0];
            a1 += w1a[k] * (float)v[1];
            a2 += w2a[k] * (float)v[2];
            a3 += w3a[k] * (float)v[3];
        }
    }
    float4 out;
    out.x = siluf(a0); out.y = siluf(a1); out.z = siluf(a2); out.w = siluf(a3);
    *reinterpret_cast<float4*>(xconv + (size_t)r * NCONV + ch) = out;
}

// ---------------------------------------------------------------------------
// Chunk decay products: chp[b*16+c] = prod_{t in chunk} dA  (parallel reduce)
// ---------------------------------------------------------------------------
__global__ __launch_bounds__(128) void chunk_prod_kernel(
    const float* __restrict__ dAv, float* __restrict__ chp)
{
    __shared__ float tmp[2];
    int blk = blockIdx.x;               // 64 = B * NCHUNK
    int tid = threadIdx.x;
    float v = dAv[blk * CHUNK + tid];
    #pragma unroll
    for (int m = 1; m <= 32; m <<= 1) v *= __shfl_xor(v, m);
    if ((tid & 63) == 0) tmp[tid >> 6] = v;
    __syncthreads();
    if (tid == 0) chp[blk] = tmp[0] * tmp[1];
}

// ---------------------------------------------------------------------------
// S1: per-chunk local state from zero.
// Thread owns 2 p x 16 n (8 named f32x4).  nt = tid&7 (n0=nt*16),
// pt = tid>>3 (p0 = pg*64 + pt*2).  dA/dt staged in LDS; B/x prefetched
// one timestep ahead (overread of 1 row at chunk end stays inside d_ws).
// cstate layout: (b, c, p, n) -> offset ((b*16+c)<<17) + p*128 + n
// ---------------------------------------------------------------------------
__global__ __launch_bounds__(256)
__attribute__((amdgpu_waves_per_eu(2, 4)))
void scan_local_kernel(
    const float* __restrict__ xconv, const float* __restrict__ dAv,
    const float* __restrict__ dtv, float* __restrict__ cstate)
{
    __shared__ float sdA[CHUNK], sdt[CHUNK];
    int blk = blockIdx.x;               // B * NCHUNK * 16 = 1024
    int b  = blk >> 8;
    int c  = (blk >> 4) & 15;
    int pg = blk & 15;
    int tid = threadIdx.x;
    int nt = tid & 7;
    int pt = tid >> 3;
    int n0 = nt * 16;
    int p0 = pg * 64 + pt * 2;

    int r0 = b * SEQLEN + c * CHUNK;
    if (tid < CHUNK) { sdA[tid] = dAv[r0 + tid]; sdt[tid] = dtv[r0 + tid]; }
    __syncthreads();

    f32x4 s0a = 0.f, s0b = 0.f, s0c = 0.f, s0d = 0.f;
    f32x4 s1a = 0.f, s1b = 0.f, s1c = 0.f, s1d = 0.f;

    const float* xc = xconv + (size_t)r0 * NCONV;
    const f32x4* Bp = reinterpret_cast<const f32x4*>(xc + DINNER + n0);
    f32x4 nb0 = Bp[0], nb1 = Bp[1], nb2 = Bp[2], nb3 = Bp[3];
    float2 nxv = *reinterpret_cast<const float2*>(xc + p0);

    for (int tl = 0; tl < CHUNK; ++tl) {
        f32x4 b0 = nb0, b1 = nb1, b2 = nb2, b3 = nb3;
        float2 xv = nxv;
        xc += NCONV;
        Bp = reinterpret_cast<const f32x4*>(xc + DINNER + n0);
        nb0 = Bp[0]; nb1 = Bp[1]; nb2 = Bp[2]; nb3 = Bp[3];
        nxv = *reinterpret_cast<const float2*>(xc + p0);

        float dA = sdA[tl], dt = sdt[tl];
        float c0 = dt * xv.x, c1 = dt * xv.y;
        s0a = s0a * dA + b0 * c0;  s0b = s0b * dA + b1 * c0;
        s0c = s0c * dA + b2 * c0;  s0d = s0d * dA + b3 * c0;
        s1a = s1a * dA + b0 * c1;  s1b = s1b * dA + b1 * c1;
        s1c = s1c * dA + b2 * c1;  s1d = s1d * dA + b3 * c1;
    }

    float* cbase = cstate + (((size_t)(b * NCHUNK + c)) << 17)
                 + (size_t)p0 * DSTATE + n0;
    f32x4* o0 = reinterpret_cast<f32x4*>(cbase);
    o0[0] = s0a; o0[1] = s0b; o0[2] = s0c; o0[3] = s0d;
    f32x4* o1 = reinterpret_cast<f32x4*>(cbase + DSTATE);
    o1[0] = s1a; o1[1] = s1b; o1[2] = s1c; o1[3] = s1d;
}

// ---------------------------------------------------------------------------
// S2: sequential combine across chunks; converts local final states into
// chunk-initial states (in place).  Element-indexed, layout-agnostic.
// ---------------------------------------------------------------------------
__global__ __launch_bounds__(256) void scan_combine_kernel(
    float* __restrict__ cstate, const float* __restrict__ chp)
{
    int idx = blockIdx.x * 256 + threadIdx.x;   // B * 131072
    int b   = idx >> 17;
    int np  = idx & 131071;
    float v = 0.f;
    for (int c = 0; c < NCHUNK; ++c) {
        size_t off = ((size_t)(b * NCHUNK + c) << 17) + np;
        float tmp = cstate[off];
        cstate[off] = v;
        v = chp[b * NCHUNK + c] * v + tmp;
    }
}

// ---------------------------------------------------------------------------
// S3: replay chunk from its initial state, emit y[r,p] = state . C_t + Dp*x
// Same 2p x 16n mapping; y reduced over the 8 n-threads via 3x shfl_xor.
// ---------------------------------------------------------------------------
__global__ __launch_bounds__(256)
__attribute__((amdgpu_waves_per_eu(2, 4)))
void scan_final_kernel(
    const float* __restrict__ xconv, const float* __restrict__ cstate,
    const float* __restrict__ dAv, const float* __restrict__ dtv,
    const float* __restrict__ Dp, float* __restrict__ yf)
{
    __shared__ float sdA[CHUNK], sdt[CHUNK];
    int blk = blockIdx.x;               // B * NCHUNK * 16 = 1024
    int b  = blk >> 8;
    int c  = (blk >> 4) & 15;
    int pg = blk & 15;
    int tid = threadIdx.x;
    int nt = tid & 7;
    int pt = tid >> 3;
    int n0 = nt * 16;
    int p0 = pg * 64 + pt * 2;

    int r0 = b * SEQLEN + c * CHUNK;
    if (tid < CHUNK) { sdA[tid] = dAv[r0 + tid]; sdt[tid] = dtv[r0 + tid]; }
    __syncthreads();

    const float* cbase = cstate + (((size_t)(b * NCHUNK + c)) << 17)
                       + (size_t)p0 * DSTATE + n0;
    const f32x4* i0 = reinterpret_cast<const f32x4*>(cbase);
    f32x4 s0a = i0[0], s0b = i0[1], s0c = i0[2], s0d = i0[3];
    const f32x4* i1 = reinterpret_cast<const f32x4*>(cbase + DSTATE);
    f32x4 s1a = i1[0], s1b = i1[1], s1c = i1[2], s1d = i1[3];

    float D0 = Dp[0];
    const float* xc = xconv + (size_t)r0 * NCONV;
    const f32x4* Bp = reinterpret_cast<const f32x4*>(xc + DINNER + n0);
    const f32x4* Cp = reinterpret_cast<const f32x4*>(xc + DINNER + DSTATE + n0);
    f32x4 nb0 = Bp[0], nb1 = Bp[1], nb2 = Bp[2], nb3 = Bp[3];
    f32x4 nc0 = Cp[0], nc1 = Cp[1], nc2 = Cp[2], nc3 = Cp[3];
    float2 nxv = *reinterpret_cast<const float2*>(xc + p0);

    for (int tl = 0; tl < CHUNK; ++tl) {
        f32x4 b0 = nb0, b1 = nb1, b2 = nb2, b3 = nb3;
        f32x4 cc0 = nc0, cc1 = nc1, cc2 = nc2, cc3 = nc3;
        float2 xv = nxv;
        xc += NCONV;
        Bp = reinterpret_cast<const f32x4*>(xc + DINNER + n0);
        Cp = reinterpret_cast<const f32x4*>(xc + DINNER + DSTATE + n0);
        nb0 = Bp[0]; nb1 = Bp[1]; nb2 = Bp[2]; nb3 = Bp[3];
        nc0 = Cp[0]; nc1 = Cp[1]; nc2 = Cp[2]; nc3 = Cp[3];
        nxv = *reinterpret_cast<const float2*>(xc + p0);

        float dA = sdA[tl], dt = sdt[tl];
        float c0 = dt * xv.x, c1 = dt * xv.y;
        s0a = s0a * dA + b0 * c0;  s0b = s0b * dA + b1 * c0;
        s0c = s0c * dA + b2 * c0;  s0d = s0d * dA + b3 * c0;
        s1a = s1a * dA + b0 * c1;  s1b = s1b * dA + b1 * c1;
        s1c = s1c * dA + b2 * c1;  s1d = s1d * dA + b3 * c1;

        f32x4 a0 = s0a * cc0;
        a0 += s0b * cc1; a0 += s0c * cc2; a0 += s0d * cc3;
        f32x4 a1 = s1a * cc0;
        a1 += s1b * cc1; a1 += s1c * cc2; a1 += s1d * cc3;
        float y0 = (a0[0] + a0[1]) + (a0[2] + a0[3]);
        float y1 = (a1[0] + a1[1]) + (a1[2] + a1[3]);
        y0 += __shfl_xor(y0, 1); y0 += __shfl_xor(y0, 2); y0 += __shfl_xor(y0, 4);
        y1 += __shfl_xor(y1, 1); y1 += __shfl_xor(y1, 2); y1 += __shfl_xor(y1, 4);
        if (nt == 0) {
            float2 o; o.x = y0 + D0 * xv.x; o.y = y1 + D0 * xv.y;
            *reinterpret_cast<float2*>(yf + (size_t)(r0 + tl) * DINNER + p0) = o;
        }
    }
}

// ---------------------------------------------------------------------------
// Gate + RMSNorm: g = y*silu(z); g *= rsqrt(mean(g^2)+eps)*norm_w -> bf16
// One block (256 thr) per row; each thread 4 elements.
// ---------------------------------------------------------------------------
__global__ __launch_bounds__(256) void gate_norm_kernel(
    const float* __restrict__ yf, const bf16_t* __restrict__ zx,
    const float* __restrict__ norm_w, bf16_t* __restrict__ yb)
{
    __shared__ float red[4];
    int r = blockIdx.x, tid = threadIdx.x;
    int p = tid * 4;
    float4 y = *reinterpret_cast<const float4*>(yf + (size_t)r * DINNER + p);
    bf16x4 zv = *reinterpret_cast<const bf16x4*>(zx + (size_t)r * NZX + p);
    float z0 = (float)zv[0], z1 = (float)zv[1], z2 = (float)zv[2], z3 = (float)zv[3];
    float g0 = y.x * siluf(z0);
    float g1 = y.y * siluf(z1);
    float g2 = y.z * siluf(z2);
    float g3 = y.w * siluf(z3);
    float ss = g0 * g0 + g1 * g1 + g2 * g2 + g3 * g3;
    #pragma unroll
    for (int m = 32; m >= 1; m >>= 1) ss += __shfl_xor(ss, m);
    if ((tid & 63) == 0) red[tid >> 6] = ss;
    __syncthreads();
    float tot = red[0] + red[1] + red[2] + red[3];
    float scale = rsqrtf(tot * (1.f / 1024.f) + 1e-5f);
    float4 nw = *reinterpret_cast<const float4*>(norm_w + p);
    bf16x4 o;
    o[0] = (bf16_t)(g0 * scale * nw.x);
    o[1] = (bf16_t)(g1 * scale * nw.y);
    o[2] = (bf16_t)(g2 * scale * nw.z);
    o[3] = (bf16_t)(g3 * scale * nw.w);
    *reinterpret_cast<bf16x4*>(yb + (size_t)r * DINNER + p) = o;
}

// ---------------------------------------------------------------------------
// rnn_state passthrough into the output tail
// ---------------------------------------------------------------------------
__global__ __launch_bounds__(256) void copy_f32_kernel(
    const float* __restrict__ in, float* __restrict__ out, int n)
{
    int i = blockIdx.x * 256 + threadIdx.x;
    if (i < n) out[i] = in[i];
}

// ---------------------------------------------------------------------------
extern "C" void kernel_launch(void* const* d_in, const int* in_sizes, int n_in,
                              void* d_out, int out_size, void* d_ws, size_t ws_size,
                              hipStream_t stream)
{
    const float* x        = (const float*)d_in[0];
    const float* rnn      = (const float*)d_in[1];
    const float* W_in     = (const float*)d_in[2];
    const float* conv_w   = (const float*)d_in[3];
    const float* conv_b   = (const float*)d_in[4];
    const float* dt_bias  = (const float*)d_in[5];
    const float* A_log    = (const float*)d_in[6];
    const float* Dp       = (const float*)d_in[7];
    const float* norm_w   = (const float*)d_in[8];
    const float* W_out    = (const float*)d_in[9];
    float* out = (float*)d_out;

    // workspace carve (all sizes multiples of 256B)
    char* ws = (char*)d_ws;
    bf16_t* xb     = (bf16_t*)(ws + 0);                       //  8,388,608
    bf16_t* winb   = (bf16_t*)(ws + 8388608);                 //  2,360,320
    bf16_t* woutb  = (bf16_t*)(ws + 10748928);                //  1,048,576
    bf16_t* zx     = (bf16_t*)(ws + 11797504);                // 37,748,736
    float*  dtv    = (float*) (ws + 49546240);                //     32,768
    float*  dAv    = (float*) (ws + 49579008);                //     32,768
    float*  chp    = (float*) (ws + 49611776);                //        256
    float*  xconv  = (float*) (ws + 49612032);                // 41,943,040
    float*  cstate = (float*) (ws + 91555072);                // 33,554,432
    float*  yf     = (float*) (ws + 125109504);               // 33,554,432
    bf16_t* yb     = (bf16_t*)(ws + 158663936);               // 16,777,216
    // total 175,441,152 bytes

    // 1) casts to bf16
    cast_bf16_kernel<<<(MROWS * DMODEL / 4 + 255) / 256, 256, 0, stream>>>(x, xb, MROWS * DMODEL / 4);
    cast_bf16_kernel<<<(2305 * DMODEL / 4 + 255) / 256, 256, 0, stream>>>(W_in, winb, 2305 * DMODEL / 4);
    cast_bf16_kernel<<<(DMODEL * DINNER / 4 + 255) / 256, 256, 0, stream>>>(W_out, woutb, DMODEL * DINNER / 4);

    // 2) dt column (fp32 exact) -> dtv, dAv ; chunk decay products
    dt_kernel<<<MROWS / 4, 256, 0, stream>>>(x, W_in, dt_bias, A_log, dtv, dAv);
    chunk_prod_kernel<<<BATCH * NCHUNK, 128, 0, stream>>>(dAv, chp);

    // 3) GEMM1: zx[8192,2304] = xb * winb^T (bf16 out)
    gemm_bf16_kernel<bf16_t><<<dim3(NZX / 128, MROWS / 128), 256, 0, stream>>>(
        xb, winb, zx, MROWS, NZX, DMODEL);

    // 4) conv + bias + silu -> xconv f32 (1280 ch)
    conv_kernel<<<MROWS * (NCONV / 4) / 256, 256, 0, stream>>>(zx, conv_w, conv_b, xconv);

    // 5) chunked scan
    scan_local_kernel<<<BATCH * NCHUNK * 16, 256, 0, stream>>>(xconv, dAv, dtv, cstate);
    scan_combine_kernel<<<BATCH * 131072 / 256, 256, 0, stream>>>(cstate, chp);
    scan_final_kernel<<<BATCH * NCHUNK * 16, 256, 0, stream>>>(xconv, cstate, dAv, dtv, Dp, yf);

    // 6) gate + RMSNorm -> yb bf16
    gate_norm_kernel<<<MROWS, 256, 0, stream>>>(yf, zx, norm_w, yb);

    // 7) GEMM2: out[8192,512] = yb * woutb^T (f32 out, directly into d_out)
    gemm_bf16_kernel<float><<<dim3(DMODEL / 128, MROWS / 128), 256, 0, stream>>>(
        yb, woutb, out, MROWS, DMODEL, DINNER);

    // 8) rnn_state passthrough
    copy_f32_kernel<<<(BATCH * DMODEL + 255) / 256, 256, 0, stream>>>(
        rnn, out + (size_t)MROWS * DMODEL, BATCH * DMODEL);
}

// Round 5
// 280.814 us; speedup vs baseline: 5.5737x; 2.1702x over previous
//
#include <hip/hip_runtime.h>
#include <cstdint>
#include <cstddef>

// ---------------------------------------------------------------------------
// Mamba2 layer forward for B=4, L=2048, d_model=512, d_inner=1024, d_state=128,
// nheads=1, headdim=1024, d_conv=4, ngroups=1.
// R4 history: per-thread scan was VMEM-issue bound (32x intra-block B/C
//   redundancy, 278us). R5: SSD rewrite — scan as chunked bf16 MFMA GEMMs:
//   G = C@B^T ; M[i,j] = G*exp(A(s_i-s_j))*dt_j (j<=i) ; Y = [M|P*C] @ [X;S]^T
//   S_loc = X^T @ (E*dt*B)^T ; sequential chunk combine for S_init.
//   Decay factors via in-chunk cumsum of dt (exact fp32, log-space stable).
// ---------------------------------------------------------------------------

typedef __bf16 bf16_t;
typedef __bf16 bf16x8 __attribute__((ext_vector_type(8)));
typedef __bf16 bf16x4 __attribute__((ext_vector_type(4)));
typedef float  f32x4  __attribute__((ext_vector_type(4)));

#define BATCH   4
#define SEQLEN  2048
#define MROWS   8192          // B*L
#define DMODEL  512
#define DINNER  1024
#define DSTATE  128
#define NZX     2304          // z(1024) + xBC(1280); dt col handled separately
#define NCONV   1280
#define CHUNK   128           // scan chunk length
#define NCHUNK  16            // SEQLEN / CHUNK
#define NBC     64            // BATCH * NCHUNK

__device__ __forceinline__ float siluf(float x) { return x / (1.f + __expf(-x)); }

// ---------------------------------------------------------------------------
// f32 -> bf16 cast (vectorized), n4 = number of float4 groups
// ---------------------------------------------------------------------------
__global__ __launch_bounds__(256) void cast_bf16_kernel(
    const float* __restrict__ in, bf16_t* __restrict__ out, int n4)
{
    int i = blockIdx.x * 256 + threadIdx.x;
    if (i < n4) {
        float4 v = reinterpret_cast<const float4*>(in)[i];
        bf16x4 o;
        o[0] = (bf16_t)v.x; o[1] = (bf16_t)v.y; o[2] = (bf16_t)v.z; o[3] = (bf16_t)v.w;
        reinterpret_cast<bf16x4*>(out)[i] = o;
    }
}

// ---------------------------------------------------------------------------
// Generic batched bf16 MFMA GEMM: C[m,n] = sum_k A[m*lda+k] * B[n*ldb+k]
// 128x128 tile per block (4 waves 2x2 of 64x64), BK=64, 16x16x32 mfma.
// blockIdx: x = n-tile, y = m-tile, z = batch (strides sA/sB/sC in elements).
// C written at C[m*Ntot + n] (Ntot = full row width).
// ---------------------------------------------------------------------------
template <typename OutT>
__global__ __launch_bounds__(256) void gemm_bt_kernel(
    const bf16_t* __restrict__ A, const bf16_t* __restrict__ B,
    OutT* __restrict__ C, int Ntot, int K, int lda, int ldb,
    size_t sA, size_t sB, size_t sC)
{
    constexpr int LDT = 72;
    __shared__ __align__(16) bf16_t As[128 * LDT];
    __shared__ __align__(16) bf16_t Bs[128 * LDT];

    A += (size_t)blockIdx.z * sA;
    B += (size_t)blockIdx.z * sB;
    C += (size_t)blockIdx.z * sC;

    const int bn = blockIdx.x, bm = blockIdx.y;
    const int tid  = threadIdx.x;
    const int wave = tid >> 6, lane = tid & 63;
    const int lr = lane & 15, q = lane >> 4;
    const int wm = (wave & 1) * 64, wn = (wave >> 1) * 64;

    f32x4 acc[4][4];
    #pragma unroll
    for (int i = 0; i < 4; ++i)
        #pragma unroll
        for (int j = 0; j < 4; ++j)
            acc[i][j] = (f32x4){0.f, 0.f, 0.f, 0.f};

    const int row_a0 = bm * 128, row_b0 = bn * 128;
    const int srow = tid >> 3, skc = tid & 7;

    for (int kt = 0; kt < K; kt += 64) {
        #pragma unroll
        for (int i = 0; i < 4; ++i) {
            int row = srow + i * 32;
            bf16x8 av = *reinterpret_cast<const bf16x8*>(
                &A[(size_t)(row_a0 + row) * lda + kt + skc * 8]);
            *reinterpret_cast<bf16x8*>(&As[row * LDT + skc * 8]) = av;
            bf16x8 bv = *reinterpret_cast<const bf16x8*>(
                &B[(size_t)(row_b0 + row) * ldb + kt + skc * 8]);
            *reinterpret_cast<bf16x8*>(&Bs[row * LDT + skc * 8]) = bv;
        }
        __syncthreads();
        #pragma unroll
        for (int k0 = 0; k0 < 64; k0 += 32) {
            bf16x8 af[4], bfr[4];
            #pragma unroll
            for (int mi = 0; mi < 4; ++mi)
                af[mi] = *reinterpret_cast<const bf16x8*>(
                    &As[(wm + mi * 16 + lr) * LDT + k0 + q * 8]);
            #pragma unroll
            for (int ni = 0; ni < 4; ++ni)
                bfr[ni] = *reinterpret_cast<const bf16x8*>(
                    &Bs[(wn + ni * 16 + lr) * LDT + k0 + q * 8]);
            #pragma unroll
            for (int mi = 0; mi < 4; ++mi)
                #pragma unroll
                for (int ni = 0; ni < 4; ++ni)
                    acc[mi][ni] = __builtin_amdgcn_mfma_f32_16x16x32_bf16(
                        af[mi], bfr[ni], acc[mi][ni], 0, 0, 0);
        }
        __syncthreads();
    }

    #pragma unroll
    for (int mi = 0; mi < 4; ++mi)
        #pragma unroll
        for (int ni = 0; ni < 4; ++ni)
            #pragma unroll
            for (int ri = 0; ri < 4; ++ri) {
                int row = row_a0 + wm + mi * 16 + q * 4 + ri;
                int col = row_b0 + wn + ni * 16 + lr;
                C[(size_t)row * Ntot + col] = (OutT)acc[mi][ni][ri];
            }
}

// ---------------------------------------------------------------------------
// Specialized Y-GEMM: Y[i,p] = sum_{k<256} Mx[i,k] * Dx[p,k]
// where Dx rows: k<128 -> Xt[p,k], k>=128 -> Stb[p,k-128].
// grid (8 n-tiles, 1, 64 chunks). Output yf fp32 [i, 1024].
// ---------------------------------------------------------------------------
__global__ __launch_bounds__(256) void gemm_y_kernel(
    const bf16_t* __restrict__ Mx, const bf16_t* __restrict__ Xt,
    const bf16_t* __restrict__ Stb, float* __restrict__ yf)
{
    constexpr int LDT = 72;
    __shared__ __align__(16) bf16_t As[128 * LDT];
    __shared__ __align__(16) bf16_t Bs[128 * LDT];

    const int bc = blockIdx.z, bn = blockIdx.x;
    const bf16_t* Ab = Mx + (size_t)bc * 32768;                      // 128x256
    const bf16_t* Xb = Xt  + (size_t)bc * 131072 + (size_t)bn * 128 * 128;
    const bf16_t* Sb = Stb + (size_t)bc * 131072 + (size_t)bn * 128 * 128;
    float* Cb = yf + (size_t)bc * 131072;

    const int tid  = threadIdx.x;
    const int wave = tid >> 6, lane = tid & 63;
    const int lr = lane & 15, q = lane >> 4;
    const int wm = (wave & 1) * 64, wn = (wave >> 1) * 64;

    f32x4 acc[4][4];
    #pragma unroll
    for (int i = 0; i < 4; ++i)
        #pragma unroll
        for (int j = 0; j < 4; ++j)
            acc[i][j] = (f32x4){0.f, 0.f, 0.f, 0.f};

    const int srow = tid >> 3, skc = tid & 7;

    for (int kt = 0; kt < 256; kt += 64) {
        const bf16_t* bsrc = (kt < 128) ? (Xb + kt) : (Sb + (kt - 128));
        #pragma unroll
        for (int i = 0; i < 4; ++i) {
            int row = srow + i * 32;
            bf16x8 av = *reinterpret_cast<const bf16x8*>(
                &Ab[(size_t)row * 256 + kt + skc * 8]);
            *reinterpret_cast<bf16x8*>(&As[row * LDT + skc * 8]) = av;
            bf16x8 bv = *reinterpret_cast<const bf16x8*>(
                &bsrc[(size_t)row * 128 + skc * 8]);
            *reinterpret_cast<bf16x8*>(&Bs[row * LDT + skc * 8]) = bv;
        }
        __syncthreads();
        #pragma unroll
        for (int k0 = 0; k0 < 64; k0 += 32) {
            bf16x8 af[4], bfr[4];
            #pragma unroll
            for (int mi = 0; mi < 4; ++mi)
                af[mi] = *reinterpret_cast<const bf16x8*>(
                    &As[(wm + mi * 16 + lr) * LDT + k0 + q * 8]);
            #pragma unroll
            for (int ni = 0; ni < 4; ++ni)
                bfr[ni] = *reinterpret_cast<const bf16x8*>(
                    &Bs[(wn + ni * 16 + lr) * LDT + k0 + q * 8]);
            #pragma unroll
            for (int mi = 0; mi < 4; ++mi)
                #pragma unroll
                for (int ni = 0; ni < 4; ++ni)
                    acc[mi][ni] = __builtin_amdgcn_mfma_f32_16x16x32_bf16(
                        af[mi], bfr[ni], acc[mi][ni], 0, 0, 0);
        }
        __syncthreads();
    }

    #pragma unroll
    for (int mi = 0; mi < 4; ++mi)
        #pragma unroll
        for (int ni = 0; ni < 4; ++ni)
            #pragma unroll
            for (int ri = 0; ri < 4; ++ri) {
                int row = wm + mi * 16 + q * 4 + ri;
                int col = bn * 128 + wn + ni * 16 + lr;
                Cb[(size_t)row * 1024 + col] = acc[mi][ni][ri];
            }
}

// ---------------------------------------------------------------------------
// dt column: dt_raw[r] = dot(x[r,:], W_in[2304,:]) ; dt = softplus(dt_raw+bias)
// ---------------------------------------------------------------------------
__global__ __launch_bounds__(256) void dt_kernel(
    const float* __restrict__ x, const float* __restrict__ W_in,
    const float* __restrict__ dt_bias, float* __restrict__ dtv)
{
    int wave = threadIdx.x >> 6, lane = threadIdx.x & 63;
    int r = blockIdx.x * 4 + wave;
    const float* xr = x + (size_t)r * DMODEL + lane * 8;
    const float* wr = W_in + (size_t)NZX * DMODEL + lane * 8;
    float4 a0 = *reinterpret_cast<const float4*>(xr);
    float4 a1 = *reinterpret_cast<const float4*>(xr + 4);
    float4 b0 = *reinterpret_cast<const float4*>(wr);
    float4 b1 = *reinterpret_cast<const float4*>(wr + 4);
    float s = a0.x * b0.x + a0.y * b0.y + a0.z * b0.z + a0.w * b0.w
            + a1.x * b1.x + a1.y * b1.y + a1.z * b1.z + a1.w * b1.w;
    #pragma unroll
    for (int m = 32; m >= 1; m >>= 1) s += __shfl_xor(s, m);
    if (lane == 0) {
        float t  = s + dt_bias[0];
        dtv[r] = (t > 20.f) ? t : log1pf(expf(t));
    }
}

// ---------------------------------------------------------------------------
// Per-chunk inclusive cumsum of dt -> decay scalars.
// sarr = s_i ; Pv = exp(A*s_i) ; EdTv = exp(A*(sT - s_i))*dt_i ; chp = exp(A*sT)
// ---------------------------------------------------------------------------
__global__ __launch_bounds__(128) void cumsum_kernel(
    const float* __restrict__ dtv, const float* __restrict__ A_log,
    float* __restrict__ sarr, float* __restrict__ Pv,
    float* __restrict__ EdTv, float* __restrict__ chp)
{
    __shared__ float w0sum, stot;
    int bc = blockIdx.x, j = threadIdx.x;
    int lane = j & 63;
    int r = bc * CHUNK + j;
    float A = -expf(A_log[0]);
    float dt = dtv[r];
    float s = dt;
    #pragma unroll
    for (int m = 1; m <= 32; m <<= 1) {
        float o = __shfl_up(s, m);
        if (lane >= m) s += o;
    }
    if (j == 63) w0sum = s;
    __syncthreads();
    if (j >= 64) s += w0sum;
    if (j == 127) stot = s;
    __syncthreads();
    float sT = stot;
    sarr[r] = s;
    Pv[r]   = expf(A * s);
    EdTv[r] = expf(A * (sT - s)) * dt;
    if (j == 127) chp[bc] = expf(A * sT);
}

// ---------------------------------------------------------------------------
// Causal depthwise conv1d (width 4) + bias + silu -> bf16 XBC_b[8192][1280]
// ---------------------------------------------------------------------------
__global__ __launch_bounds__(256) void conv_kernel(
    const bf16_t* __restrict__ zx, const float* __restrict__ cw,
    const float* __restrict__ cb, bf16_t* __restrict__ xbc)
{
    int flat = blockIdx.x * 256 + threadIdx.x;   // MROWS * 320
    int c4 = flat % (NCONV / 4);
    int r  = flat / (NCONV / 4);
    int l  = r & (SEQLEN - 1);
    int ch = c4 * 4;

    float4 w0 = *reinterpret_cast<const float4*>(cw + (size_t)(ch + 0) * 4);
    float4 w1 = *reinterpret_cast<const float4*>(cw + (size_t)(ch + 1) * 4);
    float4 w2 = *reinterpret_cast<const float4*>(cw + (size_t)(ch + 2) * 4);
    float4 w3 = *reinterpret_cast<const float4*>(cw + (size_t)(ch + 3) * 4);
    float w0a[4] = {w0.x, w0.y, w0.z, w0.w};
    float w1a[4] = {w1.x, w1.y, w1.z, w1.w};
    float w2a[4] = {w2.x, w2.y, w2.z, w2.w};
    float w3a[4] = {w3.x, w3.y, w3.z, w3.w};

    float4 bias = *reinterpret_cast<const float4*>(cb + ch);
    float a0 = bias.x, a1 = bias.y, a2 = bias.z, a3 = bias.w;

    #pragma unroll
    for (int k = 0; k < 4; ++k) {
        if (l + k >= 3) {
            bf16x4 v = *reinterpret_cast<const bf16x4*>(
                zx + (size_t)(r + k - 3) * NZX + DINNER + ch);
            a0 += w0a[k] * (float)v[0];
            a1 += w1a[k] * (float)v[1];
            a2 += w2a[k] * (float)v[2];
            a3 += w3a[k] * (float)v[3];
        }
    }
    bf16x4 o;
    o[0] = (bf16_t)siluf(a0); o[1] = (bf16_t)siluf(a1);
    o[2] = (bf16_t)siluf(a2); o[3] = (bf16_t)siluf(a3);
    *reinterpret_cast<bf16x4*>(xbc + (size_t)r * NCONV + ch) = o;
}

// ---------------------------------------------------------------------------
// LDS-tiled transpose per (chunk, 128-col group):
//  cg<8:  Xt[bc][p][j]  = XBC_b[bc*128+j][cg*128+p]
//  cg==8: Bwt[bc][n][j] = EdTv[j] * XBC_b[bc*128+j][1024+n]
// ---------------------------------------------------------------------------
__global__ __launch_bounds__(256) void transpose_kernel(
    const bf16_t* __restrict__ xbc, const float* __restrict__ EdTv,
    bf16_t* __restrict__ Xt, bf16_t* __restrict__ Bwt)
{
    constexpr int TS = 132;   // stride: 2-way LDS conflict only
    __shared__ bf16_t tile[128 * TS];
    int cg = blockIdx.x, bc = blockIdx.y;
    int tid = threadIdx.x;
    int lrow = tid >> 4, lc8 = (tid & 15) * 8;

    #pragma unroll
    for (int pass = 0; pass < 8; ++pass) {
        int row = pass * 16 + lrow;
        bf16x8 v = *reinterpret_cast<const bf16x8*>(
            xbc + (size_t)(bc * 128 + row) * NCONV + cg * 128 + lc8);
        bf16x4 lo, hi;
        #pragma unroll
        for (int m = 0; m < 4; ++m) { lo[m] = v[m]; hi[m] = v[m + 4]; }
        *reinterpret_cast<bf16x4*>(&tile[row * TS + lc8]) = lo;
        *reinterpret_cast<bf16x4*>(&tile[row * TS + lc8 + 4]) = hi;
    }
    __syncthreads();

    const bool isB = (cg == 8);
    int jo = (tid >> 4) * 8;
    float sc[8];
    #pragma unroll
    for (int m = 0; m < 8; ++m)
        sc[m] = isB ? EdTv[bc * 128 + jo + m] : 1.f;

    #pragma unroll
    for (int pass = 0; pass < 8; ++pass) {
        int oc = pass * 16 + (tid & 15);
        bf16x8 o;
        #pragma unroll
        for (int m = 0; m < 8; ++m)
            o[m] = (bf16_t)((float)tile[(jo + m) * TS + oc] * sc[m]);
        bf16_t* dst = isB
            ? (Bwt + (size_t)bc * 16384 + (size_t)oc * 128 + jo)
            : (Xt + (size_t)bc * 131072 + ((size_t)cg * 128 + oc) * 128 + jo);
        *reinterpret_cast<bf16x8*>(dst) = o;
    }
}

// ---------------------------------------------------------------------------
// Sequential chunk combine: S_init(c) = chp(c-1)*S_init(c-1) + S_loc(c-1).
// Reads S_loc fp32 (cstate, [p,n] layout), writes S_init as bf16 (Stb).
// ---------------------------------------------------------------------------
__global__ __launch_bounds__(256) void scan_combine_kernel(
    const float* __restrict__ cstate, const float* __restrict__ chp,
    bf16_t* __restrict__ Stb)
{
    int idx = blockIdx.x * 256 + threadIdx.x;   // B * 131072
    int b   = idx >> 17;
    int np  = idx & 131071;
    float v = 0.f;
    for (int c = 0; c < NCHUNK; ++c) {
        size_t off = ((size_t)(b * NCHUNK + c) << 17) + np;
        Stb[off] = (bf16_t)v;
        float tmp = cstate[off];
        v = chp[b * NCHUNK + c] * v + tmp;
    }
}

// ---------------------------------------------------------------------------
// Build Mx[bc][i][0:256] bf16:
//  cols 0-127:  M[i,j] = (j<=i) ? G[i,j]*exp(A*(s_i-s_j))*dt_j : 0
//  cols 128-255: Cw[i,n] = P_i * C[i,n]
// ---------------------------------------------------------------------------
__global__ __launch_bounds__(256) void mbuild_kernel(
    const float* __restrict__ Gbuf, const float* __restrict__ sarr,
    const float* __restrict__ dtv, const float* __restrict__ Pv,
    const float* __restrict__ A_log, const bf16_t* __restrict__ xbc,
    bf16_t* __restrict__ Mx)
{
    __shared__ float sj[CHUNK], dj[CHUNK];
    int bc = blockIdx.x, tid = threadIdx.x;
    if (tid < CHUNK) {
        sj[tid] = sarr[bc * CHUNK + tid];
        dj[tid] = dtv[bc * CHUNK + tid];
    }
    __syncthreads();
    int i = tid >> 1, half = tid & 1;
    int r = bc * CHUNK + i;
    float A = -expf(A_log[0]);
    bf16_t* orow = Mx + (size_t)bc * 32768 + (size_t)i * 256 + half * 128;
    if (half == 0) {
        const float* Gr = Gbuf + (size_t)bc * 16384 + (size_t)i * 128;
        float si = sj[i];
        for (int j0 = 0; j0 < 128; j0 += 4) {
            float4 g = *reinterpret_cast<const float4*>(Gr + j0);
            float gv[4] = {g.x, g.y, g.z, g.w};
            bf16x4 o;
            #pragma unroll
            for (int m = 0; m < 4; ++m) {
                int jj = j0 + m;
                float val = 0.f;
                if (jj <= i) val = gv[m] * expf(A * (si - sj[jj])) * dj[jj];
                o[m] = (bf16_t)val;
            }
            *reinterpret_cast<bf16x4*>(orow + j0) = o;
        }
    } else {
        float Pi = Pv[r];
        for (int n0 = 0; n0 < 128; n0 += 8) {
            bf16x8 cv = *reinterpret_cast<const bf16x8*>(
                xbc + (size_t)r * NCONV + 1152 + n0);
            bf16x8 o;
            #pragma unroll
            for (int m = 0; m < 8; ++m) o[m] = (bf16_t)((float)cv[m] * Pi);
            *reinterpret_cast<bf16x8*>(orow + n0) = o;
        }
    }
}

// ---------------------------------------------------------------------------
// Gate + RMSNorm: y = yf + D*x; g = y*silu(z); g *= rsqrt(mean g^2+eps)*norm_w
// ---------------------------------------------------------------------------
__global__ __launch_bounds__(256) void gate_norm_kernel(
    const float* __restrict__ yf, const bf16_t* __restrict__ zx,
    const bf16_t* __restrict__ xbc, const float* __restrict__ Dp,
    const float* __restrict__ norm_w, bf16_t* __restrict__ yb)
{
    __shared__ float red[4];
    int r = blockIdx.x, tid = threadIdx.x;
    int p = tid * 4;
    float D0 = Dp[0];
    float4 y = *reinterpret_cast<const float4*>(yf + (size_t)r * DINNER + p);
    bf16x4 zv = *reinterpret_cast<const bf16x4*>(zx + (size_t)r * NZX + p);
    bf16x4 xv = *reinterpret_cast<const bf16x4*>(xbc + (size_t)r * NCONV + p);
    float g0 = (y.x + D0 * (float)xv[0]) * siluf((float)zv[0]);
    float g1 = (y.y + D0 * (float)xv[1]) * siluf((float)zv[1]);
    float g2 = (y.z + D0 * (float)xv[2]) * siluf((float)zv[2]);
    float g3 = (y.w + D0 * (float)xv[3]) * siluf((float)zv[3]);
    float ss = g0 * g0 + g1 * g1 + g2 * g2 + g3 * g3;
    #pragma unroll
    for (int m = 32; m >= 1; m >>= 1) ss += __shfl_xor(ss, m);
    if ((tid & 63) == 0) red[tid >> 6] = ss;
    __syncthreads();
    float tot = red[0] + red[1] + red[2] + red[3];
    float scale = rsqrtf(tot * (1.f / 1024.f) + 1e-5f);
    float4 nw = *reinterpret_cast<const float4*>(norm_w + p);
    bf16x4 o;
    o[0] = (bf16_t)(g0 * scale * nw.x);
    o[1] = (bf16_t)(g1 * scale * nw.y);
    o[2] = (bf16_t)(g2 * scale * nw.z);
    o[3] = (bf16_t)(g3 * scale * nw.w);
    *reinterpret_cast<bf16x4*>(yb + (size_t)r * DINNER + p) = o;
}

// ---------------------------------------------------------------------------
__global__ __launch_bounds__(256) void copy_f32_kernel(
    const float* __restrict__ in, float* __restrict__ out, int n)
{
    int i = blockIdx.x * 256 + threadIdx.x;
    if (i < n) out[i] = in[i];
}

// ---------------------------------------------------------------------------
extern "C" void kernel_launch(void* const* d_in, const int* in_sizes, int n_in,
                              void* d_out, int out_size, void* d_ws, size_t ws_size,
                              hipStream_t stream)
{
    const float* x        = (const float*)d_in[0];
    const float* rnn      = (const float*)d_in[1];
    const float* W_in     = (const float*)d_in[2];
    const float* conv_w   = (const float*)d_in[3];
    const float* conv_b   = (const float*)d_in[4];
    const float* dt_bias  = (const float*)d_in[5];
    const float* A_log    = (const float*)d_in[6];
    const float* Dp       = (const float*)d_in[7];
    const float* norm_w   = (const float*)d_in[8];
    const float* W_out    = (const float*)d_in[9];
    float* out = (float*)d_out;

    // workspace carve
    char* ws = (char*)d_ws;
    bf16_t* xb     = (bf16_t*)(ws + 0);                       //  8,388,608
    float*  Gbuf   = (float*) (ws + 0);                       //  4,194,304 (alias, after GEMM1)
    bf16_t* Mx     = (bf16_t*)(ws + 4194304);                 //  4,194,304 (alias, after GEMM1)
    bf16_t* winb   = (bf16_t*)(ws + 8388608);                 //  2,360,320
    bf16_t* woutb  = (bf16_t*)(ws + 10748928);                //  1,048,576
    bf16_t* zx     = (bf16_t*)(ws + 11797504);                // 37,748,736
    float*  dtv    = (float*) (ws + 49546240);                //     32,768
    float*  sarr   = (float*) (ws + 49579008);                //     32,768
    float*  Pv     = (float*) (ws + 49611776);                //     32,768
    float*  EdTv   = (float*) (ws + 49644544);                //     32,768
    float*  chp    = (float*) (ws + 49677312);                //        256
    bf16_t* xbcb   = (bf16_t*)(ws + 49677568);                // 20,971,520
    bf16_t* Xt     = (bf16_t*)(ws + 70649088);                // 16,777,216
    bf16_t* Bwt    = (bf16_t*)(ws + 87426304);                //  2,097,152
    float*  cstate = (float*) (ws + 89523456);                // 33,554,432 (S_loc)
    float*  yf     = (float*) (ws + 89523456);                // alias: yf over dead cstate
    bf16_t* Stb    = (bf16_t*)(ws + 123077888);               // 16,777,216
    bf16_t* yb     = (bf16_t*)(ws + 139855104);               // 16,777,216
    // end: 156,632,320 bytes

    // 1) casts to bf16
    cast_bf16_kernel<<<MROWS * DMODEL / 4 / 256, 256, 0, stream>>>(x, xb, MROWS * DMODEL / 4);
    cast_bf16_kernel<<<(2305 * DMODEL / 4 + 255) / 256, 256, 0, stream>>>(W_in, winb, 2305 * DMODEL / 4);
    cast_bf16_kernel<<<DMODEL * DINNER / 4 / 256, 256, 0, stream>>>(W_out, woutb, DMODEL * DINNER / 4);

    // 2) dt column (fp32) + per-chunk decay scalars
    dt_kernel<<<MROWS / 4, 256, 0, stream>>>(x, W_in, dt_bias, dtv);
    cumsum_kernel<<<NBC, 128, 0, stream>>>(dtv, A_log, sarr, Pv, EdTv, chp);

    // 3) GEMM1: zx[8192,2304] = xb @ winb^T (bf16 out)
    gemm_bt_kernel<bf16_t><<<dim3(NZX / 128, MROWS / 128, 1), 256, 0, stream>>>(
        xb, winb, zx, NZX, DMODEL, DMODEL, DMODEL, 0, 0, 0);

    // 4) conv + bias + silu -> bf16 XBC_b
    conv_kernel<<<MROWS * (NCONV / 4) / 256, 256, 0, stream>>>(zx, conv_w, conv_b, xbcb);

    // 5) transpose: Xt (x part), Bwt (decay-scaled B part)
    transpose_kernel<<<dim3(9, NBC), 256, 0, stream>>>(xbcb, EdTv, Xt, Bwt);

    // 6) GEMM-A: S_loc[p,n] = Xt @ Bwt^T  (per chunk, fp32 out)
    gemm_bt_kernel<float><<<dim3(1, 8, NBC), 256, 0, stream>>>(
        Xt, Bwt, cstate, DSTATE, CHUNK, CHUNK, CHUNK,
        131072, 16384, 131072);

    // 7) combine -> Stb bf16 (S_init per chunk, [p,n])
    scan_combine_kernel<<<BATCH * 131072 / 256, 256, 0, stream>>>(cstate, chp, Stb);

    // 8) GEMM-G: G[i,j] = C @ B^T (per chunk, fp32)
    gemm_bt_kernel<float><<<dim3(1, 1, NBC), 256, 0, stream>>>(
        xbcb + 1152, xbcb + 1024, Gbuf, CHUNK, CHUNK, NCONV, NCONV,
        (size_t)CHUNK * NCONV, (size_t)CHUNK * NCONV, 16384);

    // 9) build Mx = [decay-masked M | P*C]
    mbuild_kernel<<<NBC, 256, 0, stream>>>(Gbuf, sarr, dtv, Pv, A_log, xbcb, Mx);

    // 10) GEMM-Y: yf[i,p] = Mx @ [Xt;Stb]^T  (scan output, fp32)
    gemm_y_kernel<<<dim3(8, 1, NBC), 256, 0, stream>>>(Mx, Xt, Stb, yf);

    // 11) gate + RMSNorm (+ D*x) -> yb bf16
    gate_norm_kernel<<<MROWS, 256, 0, stream>>>(yf, zx, xbcb, Dp, norm_w, yb);

    // 12) GEMM2: out[8192,512] = yb @ woutb^T (f32, into d_out)
    gemm_bt_kernel<float><<<dim3(DMODEL / 128, MROWS / 128, 1), 256, 0, stream>>>(
        yb, woutb, out, DMODEL, DINNER, DINNER, DINNER, 0, 0, 0);

    // 13) rnn_state passthrough
    copy_f32_kernel<<<(BATCH * DMODEL + 255) / 256, 256, 0, stream>>>(
        rnn, out + (size_t)MROWS * DMODEL, BATCH * DMODEL);
}

// Round 6
// 263.502 us; speedup vs baseline: 5.9399x; 1.0657x over previous
//
#include <hip/hip_runtime.h>
#include <cstdint>
#include <cstddef>

// ---------------------------------------------------------------------------
// Mamba2 layer forward (B=4, L=2048, d_model=512, d_inner=1024, d_state=128,
// nheads=1, d_conv=4). SSD formulation: scan as chunked bf16 MFMA GEMMs.
// R5: SSD rewrite (609->281us). R6: global_load_lds width-16 staging in all
//   MFMA kernels (m97 pattern); GEMM-G fused into mbuild (MFMA in-kernel);
//   x-cast fused into dt_kernel; weight casts merged. 13 launches.
// ---------------------------------------------------------------------------

typedef __bf16 bf16_t;
typedef __bf16 bf16x8 __attribute__((ext_vector_type(8)));
typedef __bf16 bf16x4 __attribute__((ext_vector_type(4)));
typedef float  f32x4  __attribute__((ext_vector_type(4)));

#define BATCH   4
#define SEQLEN  2048
#define MROWS   8192
#define DMODEL  512
#define DINNER  1024
#define DSTATE  128
#define NZX     2304
#define NCONV   1280
#define CHUNK   128
#define NCHUNK  16
#define NBC     64            // BATCH * NCHUNK

__device__ __forceinline__ float siluf(float x) { return x / (1.f + __expf(-x)); }

// async global->LDS, 16B per lane. LDS dst must be wave-uniform base + lane*16.
__device__ __forceinline__ void load_lds16(const bf16_t* g, bf16_t* l)
{
    __builtin_amdgcn_global_load_lds(
        (const __attribute__((address_space(1))) void*)g,
        (__attribute__((address_space(3))) void*)l,
        16, 0, 0);
}

// ---------------------------------------------------------------------------
// merged weight casts: W_in (n4a float4 groups) then W_out (n4b groups)
// ---------------------------------------------------------------------------
__global__ __launch_bounds__(256) void cast2_kernel(
    const float* __restrict__ in1, bf16_t* __restrict__ out1, int n4a,
    const float* __restrict__ in2, bf16_t* __restrict__ out2, int n4b)
{
    int i = blockIdx.x * 256 + threadIdx.x;
    const float* src; bf16_t* dst; int j;
    if (i < n4a)           { src = in1; dst = out1; j = i; }
    else if (i < n4a + n4b){ src = in2; dst = out2; j = i - n4a; }
    else return;
    float4 v = reinterpret_cast<const float4*>(src)[j];
    bf16x4 o;
    o[0] = (bf16_t)v.x; o[1] = (bf16_t)v.y; o[2] = (bf16_t)v.z; o[3] = (bf16_t)v.w;
    reinterpret_cast<bf16x4*>(dst)[j] = o;
}

// ---------------------------------------------------------------------------
// Generic batched bf16 MFMA GEMM: C[m,n] = sum_k A[m*lda+k] * B[n*ldb+k]
// 128x128 tile (4 waves 2x2 of 64x64), BK=64, 16x16x32 mfma,
// global_load_lds staging into unpadded [128][64] LDS tiles.
// ---------------------------------------------------------------------------
template <typename OutT>
__global__ __launch_bounds__(256) void gemm_bt_kernel(
    const bf16_t* __restrict__ A, const bf16_t* __restrict__ B,
    OutT* __restrict__ C, int Ntot, int K, int lda, int ldb,
    size_t sA, size_t sB, size_t sC)
{
    __shared__ __align__(16) bf16_t As[128 * 64];
    __shared__ __align__(16) bf16_t Bs[128 * 64];

    A += (size_t)blockIdx.z * sA;
    B += (size_t)blockIdx.z * sB;
    C += (size_t)blockIdx.z * sC;

    const int bn = blockIdx.x, bm = blockIdx.y;
    const int tid  = threadIdx.x;
    const int wave = tid >> 6, lane = tid & 63;
    const int lr = lane & 15, q = lane >> 4;
    const int wm = (wave & 1) * 64, wn = (wave >> 1) * 64;

    f32x4 acc[4][4];
    #pragma unroll
    for (int i = 0; i < 4; ++i)
        #pragma unroll
        for (int j = 0; j < 4; ++j)
            acc[i][j] = (f32x4){0.f, 0.f, 0.f, 0.f};

    const int row_a0 = bm * 128, row_b0 = bn * 128;
    const int srow = tid >> 3, sc8 = (tid & 7) * 8;

    for (int kt = 0; kt < K; kt += 64) {
        #pragma unroll
        for (int i = 0; i < 4; ++i) {
            int row = srow + i * 32;
            load_lds16(&A[(size_t)(row_a0 + row) * lda + kt + sc8], &As[row * 64 + sc8]);
            load_lds16(&B[(size_t)(row_b0 + row) * ldb + kt + sc8], &Bs[row * 64 + sc8]);
        }
        __syncthreads();
        #pragma unroll
        for (int k0 = 0; k0 < 64; k0 += 32) {
            bf16x8 af[4], bfr[4];
            #pragma unroll
            for (int mi = 0; mi < 4; ++mi)
                af[mi] = *reinterpret_cast<const bf16x8*>(
                    &As[(wm + mi * 16 + lr) * 64 + k0 + q * 8]);
            #pragma unroll
            for (int ni = 0; ni < 4; ++ni)
                bfr[ni] = *reinterpret_cast<const bf16x8*>(
                    &Bs[(wn + ni * 16 + lr) * 64 + k0 + q * 8]);
            #pragma unroll
            for (int mi = 0; mi < 4; ++mi)
                #pragma unroll
                for (int ni = 0; ni < 4; ++ni)
                    acc[mi][ni] = __builtin_amdgcn_mfma_f32_16x16x32_bf16(
                        af[mi], bfr[ni], acc[mi][ni], 0, 0, 0);
        }
        __syncthreads();
    }

    #pragma unroll
    for (int mi = 0; mi < 4; ++mi)
        #pragma unroll
        for (int ni = 0; ni < 4; ++ni)
            #pragma unroll
            for (int ri = 0; ri < 4; ++ri) {
                int row = row_a0 + wm + mi * 16 + q * 4 + ri;
                int col = row_b0 + wn + ni * 16 + lr;
                C[(size_t)row * Ntot + col] = (OutT)acc[mi][ni][ri];
            }
}

// ---------------------------------------------------------------------------
// Y-GEMM: Y[i,p] = sum_{k<256} Mx[i,k] * Dx[p,k]; Dx = [Xt | Stb] per chunk.
// ---------------------------------------------------------------------------
__global__ __launch_bounds__(256) void gemm_y_kernel(
    const bf16_t* __restrict__ Mx, const bf16_t* __restrict__ Xt,
    const bf16_t* __restrict__ Stb, float* __restrict__ yf)
{
    __shared__ __align__(16) bf16_t As[128 * 64];
    __shared__ __align__(16) bf16_t Bs[128 * 64];

    const int bc = blockIdx.z, bn = blockIdx.x;
    const bf16_t* Ab = Mx + (size_t)bc * 32768;                      // 128x256
    const bf16_t* Xb = Xt  + (size_t)bc * 131072 + (size_t)bn * 128 * 128;
    const bf16_t* Sb = Stb + (size_t)bc * 131072 + (size_t)bn * 128 * 128;
    float* Cb = yf + (size_t)bc * 131072;

    const int tid  = threadIdx.x;
    const int wave = tid >> 6, lane = tid & 63;
    const int lr = lane & 15, q = lane >> 4;
    const int wm = (wave & 1) * 64, wn = (wave >> 1) * 64;

    f32x4 acc[4][4];
    #pragma unroll
    for (int i = 0; i < 4; ++i)
        #pragma unroll
        for (int j = 0; j < 4; ++j)
            acc[i][j] = (f32x4){0.f, 0.f, 0.f, 0.f};

    const int srow = tid >> 3, sc8 = (tid & 7) * 8;

    for (int kt = 0; kt < 256; kt += 64) {
        const bf16_t* bsrc = (kt < 128) ? (Xb + kt) : (Sb + (kt - 128));
        #pragma unroll
        for (int i = 0; i < 4; ++i) {
            int row = srow + i * 32;
            load_lds16(&Ab[(size_t)row * 256 + kt + sc8], &As[row * 64 + sc8]);
            load_lds16(&bsrc[(size_t)row * 128 + sc8], &Bs[row * 64 + sc8]);
        }
        __syncthreads();
        #pragma unroll
        for (int k0 = 0; k0 < 64; k0 += 32) {
            bf16x8 af[4], bfr[4];
            #pragma unroll
            for (int mi = 0; mi < 4; ++mi)
                af[mi] = *reinterpret_cast<const bf16x8*>(
                    &As[(wm + mi * 16 + lr) * 64 + k0 + q * 8]);
            #pragma unroll
            for (int ni = 0; ni < 4; ++ni)
                bfr[ni] = *reinterpret_cast<const bf16x8*>(
                    &Bs[(wn + ni * 16 + lr) * 64 + k0 + q * 8]);
            #pragma unroll
            for (int mi = 0; mi < 4; ++mi)
                #pragma unroll
                for (int ni = 0; ni < 4; ++ni)
                    acc[mi][ni] = __builtin_amdgcn_mfma_f32_16x16x32_bf16(
                        af[mi], bfr[ni], acc[mi][ni], 0, 0, 0);
        }
        __syncthreads();
    }

    #pragma unroll
    for (int mi = 0; mi < 4; ++mi)
        #pragma unroll
        for (int ni = 0; ni < 4; ++ni)
            #pragma unroll
            for (int ri = 0; ri < 4; ++ri) {
                int row = wm + mi * 16 + q * 4 + ri;
                int col = bn * 128 + wn + ni * 16 + lr;
                Cb[(size_t)row * 1024 + col] = acc[mi][ni][ri];
            }
}

// ---------------------------------------------------------------------------
// dt column + fused x->bf16 cast.  One wave per row.
// ---------------------------------------------------------------------------
__global__ __launch_bounds__(256) void dt_kernel(
    const float* __restrict__ x, const float* __restrict__ W_in,
    const float* __restrict__ dt_bias, float* __restrict__ dtv,
    bf16_t* __restrict__ xb)
{
    int wave = threadIdx.x >> 6, lane = threadIdx.x & 63;
    int r = blockIdx.x * 4 + wave;
    const float* xr = x + (size_t)r * DMODEL + lane * 8;
    const float* wr = W_in + (size_t)NZX * DMODEL + lane * 8;
    float4 a0 = *reinterpret_cast<const float4*>(xr);
    float4 a1 = *reinterpret_cast<const float4*>(xr + 4);
    float4 b0 = *reinterpret_cast<const float4*>(wr);
    float4 b1 = *reinterpret_cast<const float4*>(wr + 4);

    bf16x8 xo;
    xo[0] = (bf16_t)a0.x; xo[1] = (bf16_t)a0.y; xo[2] = (bf16_t)a0.z; xo[3] = (bf16_t)a0.w;
    xo[4] = (bf16_t)a1.x; xo[5] = (bf16_t)a1.y; xo[6] = (bf16_t)a1.z; xo[7] = (bf16_t)a1.w;
    *reinterpret_cast<bf16x8*>(xb + (size_t)r * DMODEL + lane * 8) = xo;

    float s = a0.x * b0.x + a0.y * b0.y + a0.z * b0.z + a0.w * b0.w
            + a1.x * b1.x + a1.y * b1.y + a1.z * b1.z + a1.w * b1.w;
    #pragma unroll
    for (int m = 32; m >= 1; m >>= 1) s += __shfl_xor(s, m);
    if (lane == 0) {
        float t  = s + dt_bias[0];
        dtv[r] = (t > 20.f) ? t : log1pf(expf(t));
    }
}

// ---------------------------------------------------------------------------
// Per-chunk inclusive cumsum of dt -> decay scalars.
// ---------------------------------------------------------------------------
__global__ __launch_bounds__(128) void cumsum_kernel(
    const float* __restrict__ dtv, const float* __restrict__ A_log,
    float* __restrict__ sarr, float* __restrict__ Pv,
    float* __restrict__ EdTv, float* __restrict__ chp)
{
    __shared__ float w0sum, stot;
    int bc = blockIdx.x, j = threadIdx.x;
    int lane = j & 63;
    int r = bc * CHUNK + j;
    float A = -expf(A_log[0]);
    float dt = dtv[r];
    float s = dt;
    #pragma unroll
    for (int m = 1; m <= 32; m <<= 1) {
        float o = __shfl_up(s, m);
        if (lane >= m) s += o;
    }
    if (j == 63) w0sum = s;
    __syncthreads();
    if (j >= 64) s += w0sum;
    if (j == 127) stot = s;
    __syncthreads();
    float sT = stot;
    sarr[r] = s;
    Pv[r]   = expf(A * s);
    EdTv[r] = expf(A * (sT - s)) * dt;
    if (j == 127) chp[bc] = expf(A * sT);
}

// ---------------------------------------------------------------------------
// Causal depthwise conv1d (width 4) + bias + silu -> bf16 XBC_b[8192][1280]
// ---------------------------------------------------------------------------
__global__ __launch_bounds__(256) void conv_kernel(
    const bf16_t* __restrict__ zx, const float* __restrict__ cw,
    const float* __restrict__ cb, bf16_t* __restrict__ xbc)
{
    int flat = blockIdx.x * 256 + threadIdx.x;
    int c4 = flat % (NCONV / 4);
    int r  = flat / (NCONV / 4);
    int l  = r & (SEQLEN - 1);
    int ch = c4 * 4;

    float4 w0 = *reinterpret_cast<const float4*>(cw + (size_t)(ch + 0) * 4);
    float4 w1 = *reinterpret_cast<const float4*>(cw + (size_t)(ch + 1) * 4);
    float4 w2 = *reinterpret_cast<const float4*>(cw + (size_t)(ch + 2) * 4);
    float4 w3 = *reinterpret_cast<const float4*>(cw + (size_t)(ch + 3) * 4);
    float w0a[4] = {w0.x, w0.y, w0.z, w0.w};
    float w1a[4] = {w1.x, w1.y, w1.z, w1.w};
    float w2a[4] = {w2.x, w2.y, w2.z, w2.w};
    float w3a[4] = {w3.x, w3.y, w3.z, w3.w};

    float4 bias = *reinterpret_cast<const float4*>(cb + ch);
    float a0 = bias.x, a1 = bias.y, a2 = bias.z, a3 = bias.w;

    #pragma unroll
    for (int k = 0; k < 4; ++k) {
        if (l + k >= 3) {
            bf16x4 v = *reinterpret_cast<const bf16x4*>(
                zx + (size_t)(r + k - 3) * NZX + DINNER + ch);
            a0 += w0a[k] * (float)v[0];
            a1 += w1a[k] * (float)v[1];
            a2 += w2a[k] * (float)v[2];
            a3 += w3a[k] * (float)v[3];
        }
    }
    bf16x4 o;
    o[0] = (bf16_t)siluf(a0); o[1] = (bf16_t)siluf(a1);
    o[2] = (bf16_t)siluf(a2); o[3] = (bf16_t)siluf(a3);
    *reinterpret_cast<bf16x4*>(xbc + (size_t)r * NCONV + ch) = o;
}

// ---------------------------------------------------------------------------
// LDS-tiled transpose per (chunk, 128-col group):
//  cg<8:  Xt[bc][p][j]  = XBC_b[bc*128+j][cg*128+p]
//  cg==8: Bwt[bc][n][j] = EdTv[j] * XBC_b[bc*128+j][1024+n]
// ---------------------------------------------------------------------------
__global__ __launch_bounds__(256) void transpose_kernel(
    const bf16_t* __restrict__ xbc, const float* __restrict__ EdTv,
    bf16_t* __restrict__ Xt, bf16_t* __restrict__ Bwt)
{
    constexpr int TS = 132;
    __shared__ bf16_t tile[128 * TS];
    int cg = blockIdx.x, bc = blockIdx.y;
    int tid = threadIdx.x;
    int lrow = tid >> 4, lc8 = (tid & 15) * 8;

    #pragma unroll
    for (int pass = 0; pass < 8; ++pass) {
        int row = pass * 16 + lrow;
        bf16x8 v = *reinterpret_cast<const bf16x8*>(
            xbc + (size_t)(bc * 128 + row) * NCONV + cg * 128 + lc8);
        bf16x4 lo, hi;
        #pragma unroll
        for (int m = 0; m < 4; ++m) { lo[m] = v[m]; hi[m] = v[m + 4]; }
        *reinterpret_cast<bf16x4*>(&tile[row * TS + lc8]) = lo;
        *reinterpret_cast<bf16x4*>(&tile[row * TS + lc8 + 4]) = hi;
    }
    __syncthreads();

    const bool isB = (cg == 8);
    int jo = (tid >> 4) * 8;
    float sc[8];
    #pragma unroll
    for (int m = 0; m < 8; ++m)
        sc[m] = isB ? EdTv[bc * 128 + jo + m] : 1.f;

    #pragma unroll
    for (int pass = 0; pass < 8; ++pass) {
        int oc = pass * 16 + (tid & 15);
        bf16x8 o;
        #pragma unroll
        for (int m = 0; m < 8; ++m)
            o[m] = (bf16_t)((float)tile[(jo + m) * TS + oc] * sc[m]);
        bf16_t* dst = isB
            ? (Bwt + (size_t)bc * 16384 + (size_t)oc * 128 + jo)
            : (Xt + (size_t)bc * 131072 + ((size_t)cg * 128 + oc) * 128 + jo);
        *reinterpret_cast<bf16x8*>(dst) = o;
    }
}

// ---------------------------------------------------------------------------
// Sequential chunk combine: S_init(c) = chp(c-1)*S_init(c-1) + S_loc(c-1)
// ---------------------------------------------------------------------------
__global__ __launch_bounds__(256) void scan_combine_kernel(
    const float* __restrict__ cstate, const float* __restrict__ chp,
    bf16_t* __restrict__ Stb)
{
    int idx = blockIdx.x * 256 + threadIdx.x;   // B * 131072
    int b   = idx >> 17;
    int np  = idx & 131071;
    float v = 0.f;
    for (int c = 0; c < NCHUNK; ++c) {
        size_t off = ((size_t)(b * NCHUNK + c) << 17) + np;
        Stb[off] = (bf16_t)v;
        float tmp = cstate[off];
        v = chp[b * NCHUNK + c] * v + tmp;
    }
}

// ---------------------------------------------------------------------------
// mbuild (fused GEMM-G): per chunk, stage C,B tiles via load_lds, MFMA
// G = C@B^T, then write Mx = [mask-decay(G) | P*C] bf16.
// ---------------------------------------------------------------------------
__global__ __launch_bounds__(256) void mbuild_kernel(
    const float* __restrict__ sarr, const float* __restrict__ dtv,
    const float* __restrict__ Pv, const float* __restrict__ A_log,
    const bf16_t* __restrict__ xbc, bf16_t* __restrict__ Mx)
{
    __shared__ __align__(16) bf16_t Cs[128 * 128];
    __shared__ __align__(16) bf16_t Bs2[128 * 128];
    __shared__ float sj[CHUNK], dj[CHUNK], pj[CHUNK];

    int bc = blockIdx.x, tid = threadIdx.x;
    if (tid < CHUNK) {
        sj[tid] = sarr[bc * CHUNK + tid];
        dj[tid] = dtv[bc * CHUNK + tid];
        pj[tid] = Pv[bc * CHUNK + tid];
    }
    int rowbase = bc * 128;
    int srow = tid >> 4, sc8 = (tid & 15) * 8;
    #pragma unroll
    for (int i = 0; i < 8; ++i) {
        int row = srow + i * 16;
        load_lds16(&xbc[(size_t)(rowbase + row) * NCONV + 1152 + sc8], &Cs[row * 128 + sc8]);
        load_lds16(&xbc[(size_t)(rowbase + row) * NCONV + 1024 + sc8], &Bs2[row * 128 + sc8]);
    }
    __syncthreads();

    const int wave = tid >> 6, lane = tid & 63;
    const int lr = lane & 15, q = lane >> 4;
    const int wm = (wave & 1) * 64, wn = (wave >> 1) * 64;

    f32x4 acc[4][4];
    #pragma unroll
    for (int i = 0; i < 4; ++i)
        #pragma unroll
        for (int j = 0; j < 4; ++j)
            acc[i][j] = (f32x4){0.f, 0.f, 0.f, 0.f};

    #pragma unroll
    for (int k0 = 0; k0 < 128; k0 += 32) {
        bf16x8 af[4], bfr[4];
        #pragma unroll
        for (int mi = 0; mi < 4; ++mi)
            af[mi] = *reinterpret_cast<const bf16x8*>(
                &Cs[(wm + mi * 16 + lr) * 128 + k0 + q * 8]);
        #pragma unroll
        for (int ni = 0; ni < 4; ++ni)
            bfr[ni] = *reinterpret_cast<const bf16x8*>(
                &Bs2[(wn + ni * 16 + lr) * 128 + k0 + q * 8]);
        #pragma unroll
        for (int mi = 0; mi < 4; ++mi)
            #pragma unroll
            for (int ni = 0; ni < 4; ++ni)
                acc[mi][ni] = __builtin_amdgcn_mfma_f32_16x16x32_bf16(
                    af[mi], bfr[ni], acc[mi][ni], 0, 0, 0);
    }

    float A = -expf(A_log[0]);
    bf16_t* MxB = Mx + (size_t)bc * 32768;
    #pragma unroll
    for (int mi = 0; mi < 4; ++mi)
        #pragma unroll
        for (int ni = 0; ni < 4; ++ni)
            #pragma unroll
            for (int ri = 0; ri < 4; ++ri) {
                int row = wm + mi * 16 + q * 4 + ri;
                int col = wn + ni * 16 + lr;
                float val = 0.f;
                if (col <= row)
                    val = acc[mi][ni][ri] * expf(A * (sj[row] - sj[col])) * dj[col];
                MxB[(size_t)row * 256 + col] = (bf16_t)val;
            }

    // Cw half from LDS: Mx[row][128+n] = P_row * C[row][n]
    int rr = tid >> 1, cb = (tid & 1) * 64;
    float Pi = pj[rr];
    #pragma unroll
    for (int m0 = 0; m0 < 64; m0 += 8) {
        bf16x8 cv = *reinterpret_cast<const bf16x8*>(&Cs[rr * 128 + cb + m0]);
        bf16x8 o;
        #pragma unroll
        for (int m = 0; m < 8; ++m) o[m] = (bf16_t)((float)cv[m] * Pi);
        *reinterpret_cast<bf16x8*>(&MxB[(size_t)rr * 256 + 128 + cb + m0]) = o;
    }
}

// ---------------------------------------------------------------------------
// Gate + RMSNorm: y = yf + D*x; g = y*silu(z); g *= rsqrt(mean g^2+eps)*norm_w
// ---------------------------------------------------------------------------
__global__ __launch_bounds__(256) void gate_norm_kernel(
    const float* __restrict__ yf, const bf16_t* __restrict__ zx,
    const bf16_t* __restrict__ xbc, const float* __restrict__ Dp,
    const float* __restrict__ norm_w, bf16_t* __restrict__ yb)
{
    __shared__ float red[4];
    int r = blockIdx.x, tid = threadIdx.x;
    int p = tid * 4;
    float D0 = Dp[0];
    float4 y = *reinterpret_cast<const float4*>(yf + (size_t)r * DINNER + p);
    bf16x4 zv = *reinterpret_cast<const bf16x4*>(zx + (size_t)r * NZX + p);
    bf16x4 xv = *reinterpret_cast<const bf16x4*>(xbc + (size_t)r * NCONV + p);
    float g0 = (y.x + D0 * (float)xv[0]) * siluf((float)zv[0]);
    float g1 = (y.y + D0 * (float)xv[1]) * siluf((float)zv[1]);
    float g2 = (y.z + D0 * (float)xv[2]) * siluf((float)zv[2]);
    float g3 = (y.w + D0 * (float)xv[3]) * siluf((float)zv[3]);
    float ss = g0 * g0 + g1 * g1 + g2 * g2 + g3 * g3;
    #pragma unroll
    for (int m = 32; m >= 1; m >>= 1) ss += __shfl_xor(ss, m);
    if ((tid & 63) == 0) red[tid >> 6] = ss;
    __syncthreads();
    float tot = red[0] + red[1] + red[2] + red[3];
    float scale = rsqrtf(tot * (1.f / 1024.f) + 1e-5f);
    float4 nw = *reinterpret_cast<const float4*>(norm_w + p);
    bf16x4 o;
    o[0] = (bf16_t)(g0 * scale * nw.x);
    o[1] = (bf16_t)(g1 * scale * nw.y);
    o[2] = (bf16_t)(g2 * scale * nw.z);
    o[3] = (bf16_t)(g3 * scale * nw.w);
    *reinterpret_cast<bf16x4*>(yb + (size_t)r * DINNER + p) = o;
}

// ---------------------------------------------------------------------------
__global__ __launch_bounds__(256) void copy_f32_kernel(
    const float* __restrict__ in, float* __restrict__ out, int n)
{
    int i = blockIdx.x * 256 + threadIdx.x;
    if (i < n) out[i] = in[i];
}

// ---------------------------------------------------------------------------
extern "C" void kernel_launch(void* const* d_in, const int* in_sizes, int n_in,
                              void* d_out, int out_size, void* d_ws, size_t ws_size,
                              hipStream_t stream)
{
    const float* x        = (const float*)d_in[0];
    const float* rnn      = (const float*)d_in[1];
    const float* W_in     = (const float*)d_in[2];
    const float* conv_w   = (const float*)d_in[3];
    const float* conv_b   = (const float*)d_in[4];
    const float* dt_bias  = (const float*)d_in[5];
    const float* A_log    = (const float*)d_in[6];
    const float* Dp       = (const float*)d_in[7];
    const float* norm_w   = (const float*)d_in[8];
    const float* W_out    = (const float*)d_in[9];
    float* out = (float*)d_out;

    // workspace carve
    char* ws = (char*)d_ws;
    bf16_t* xb     = (bf16_t*)(ws + 0);                       //  8,388,608
    bf16_t* Mx     = (bf16_t*)(ws + 4194304);                 //  4,194,304 (alias over xb tail, after GEMM1)
    bf16_t* winb   = (bf16_t*)(ws + 8388608);                 //  2,360,320
    bf16_t* woutb  = (bf16_t*)(ws + 10748928);                //  1,048,576
    bf16_t* zx     = (bf16_t*)(ws + 11797504);                // 37,748,736
    float*  dtv    = (float*) (ws + 49546240);                //     32,768
    float*  sarr   = (float*) (ws + 49579008);                //     32,768
    float*  Pv     = (float*) (ws + 49611776);                //     32,768
    float*  EdTv   = (float*) (ws + 49644544);                //     32,768
    float*  chp    = (float*) (ws + 49677312);                //        256
    bf16_t* xbcb   = (bf16_t*)(ws + 49677568);                // 20,971,520
    bf16_t* Xt     = (bf16_t*)(ws + 70649088);                // 16,777,216
    bf16_t* Bwt    = (bf16_t*)(ws + 87426304);                //  2,097,152
    float*  cstate = (float*) (ws + 89523456);                // 33,554,432 (S_loc)
    float*  yf     = (float*) (ws + 89523456);                // alias over dead cstate
    bf16_t* Stb    = (bf16_t*)(ws + 123077888);               // 16,777,216
    bf16_t* yb     = (bf16_t*)(ws + 139855104);               // 16,777,216
    // end: 156,632,320 bytes

    // 1) dt column (fp32) + fused x->bf16 cast; merged weight casts
    dt_kernel<<<MROWS / 4, 256, 0, stream>>>(x, W_in, dt_bias, dtv, xb);
    {
        int n4a = 2305 * DMODEL / 4, n4b = DMODEL * DINNER / 4;
        cast2_kernel<<<(n4a + n4b + 255) / 256, 256, 0, stream>>>(
            W_in, winb, n4a, W_out, woutb, n4b);
    }
    cumsum_kernel<<<NBC, 128, 0, stream>>>(dtv, A_log, sarr, Pv, EdTv, chp);

    // 2) GEMM1: zx[8192,2304] = xb @ winb^T (bf16 out)
    gemm_bt_kernel<bf16_t><<<dim3(NZX / 128, MROWS / 128, 1), 256, 0, stream>>>(
        xb, winb, zx, NZX, DMODEL, DMODEL, DMODEL, 0, 0, 0);

    // 3) conv + bias + silu -> bf16 XBC_b
    conv_kernel<<<MROWS * (NCONV / 4) / 256, 256, 0, stream>>>(zx, conv_w, conv_b, xbcb);

    // 4) transpose: Xt (x part), Bwt (decay-scaled B part)
    transpose_kernel<<<dim3(9, NBC), 256, 0, stream>>>(xbcb, EdTv, Xt, Bwt);

    // 5) GEMM-A: S_loc[p,n] = Xt @ Bwt^T  (per chunk, fp32 out)
    gemm_bt_kernel<float><<<dim3(1, 8, NBC), 256, 0, stream>>>(
        Xt, Bwt, cstate, DSTATE, CHUNK, CHUNK, CHUNK,
        131072, 16384, 131072);

    // 6) combine -> Stb bf16 (S_init per chunk, [p,n])
    scan_combine_kernel<<<BATCH * 131072 / 256, 256, 0, stream>>>(cstate, chp, Stb);

    // 7) mbuild (fused G-GEMM): Mx = [decay-masked C@B^T | P*C]
    mbuild_kernel<<<NBC, 256, 0, stream>>>(sarr, dtv, Pv, A_log, xbcb, Mx);

    // 8) GEMM-Y: yf[i,p] = Mx @ [Xt;Stb]^T  (scan output, fp32)
    gemm_y_kernel<<<dim3(8, 1, NBC), 256, 0, stream>>>(Mx, Xt, Stb, yf);

    // 9) gate + RMSNorm (+ D*x) -> yb bf16
    gate_norm_kernel<<<MROWS, 256, 0, stream>>>(yf, zx, xbcb, Dp, norm_w, yb);

    // 10) GEMM2: out[8192,512] = yb @ woutb^T (f32, into d_out)
    gemm_bt_kernel<float><<<dim3(DMODEL / 128, MROWS / 128, 1), 256, 0, stream>>>(
        yb, woutb, out, DMODEL, DINNER, DINNER, DINNER, 0, 0, 0);

    // 11) rnn_state passthrough
    copy_f32_kernel<<<(BATCH * DMODEL + 255) / 256, 256, 0, stream>>>(
        rnn, out + (size_t)MROWS * DMODEL, BATCH * DMODEL);
}

// Round 7
// 253.207 us; speedup vs baseline: 6.1814x; 1.0407x over previous
//
#include <hip/hip_runtime.h>
#include <cstdint>
#include <cstddef>

// ---------------------------------------------------------------------------
// Mamba2 layer forward (B=4, L=2048, d_model=512, d_inner=1024, d_state=128,
// nheads=1, d_conv=4). SSD formulation: scan as chunked bf16 MFMA GEMMs.
// R5: SSD rewrite (609->281us). R6: global_load_lds staging (281->263) BUT
//   unpadded LDS tile -> 16-way ds_read bank conflicts (7.08M cycles, GEMM1
//   41->50us). R7: XOR swizzle — stage global chunk kg^(row&7) into slot
//   (row,kg); read chunk kc from slot (r, kc^(r&7)). 2-way aliasing = free.
// ---------------------------------------------------------------------------

typedef __bf16 bf16_t;
typedef __bf16 bf16x8 __attribute__((ext_vector_type(8)));
typedef __bf16 bf16x4 __attribute__((ext_vector_type(4)));
typedef float  f32x4  __attribute__((ext_vector_type(4)));

#define BATCH   4
#define SEQLEN  2048
#define MROWS   8192
#define DMODEL  512
#define DINNER  1024
#define DSTATE  128
#define NZX     2304
#define NCONV   1280
#define CHUNK   128
#define NCHUNK  16
#define NBC     64            // BATCH * NCHUNK

__device__ __forceinline__ float siluf(float x) { return x / (1.f + __expf(-x)); }

// async global->LDS, 16B per lane. LDS dst is wave-uniform base + lane*16.
__device__ __forceinline__ void load_lds16(const bf16_t* g, bf16_t* l)
{
    __builtin_amdgcn_global_load_lds(
        (const __attribute__((address_space(1))) void*)g,
        (__attribute__((address_space(3))) void*)l,
        16, 0, 0);
}

// ---------------------------------------------------------------------------
// merged weight casts: W_in (n4a float4 groups) then W_out (n4b groups)
// ---------------------------------------------------------------------------
__global__ __launch_bounds__(256) void cast2_kernel(
    const float* __restrict__ in1, bf16_t* __restrict__ out1, int n4a,
    const float* __restrict__ in2, bf16_t* __restrict__ out2, int n4b)
{
    int i = blockIdx.x * 256 + threadIdx.x;
    const float* src; bf16_t* dst; int j;
    if (i < n4a)           { src = in1; dst = out1; j = i; }
    else if (i < n4a + n4b){ src = in2; dst = out2; j = i - n4a; }
    else return;
    float4 v = reinterpret_cast<const float4*>(src)[j];
    bf16x4 o;
    o[0] = (bf16_t)v.x; o[1] = (bf16_t)v.y; o[2] = (bf16_t)v.z; o[3] = (bf16_t)v.w;
    reinterpret_cast<bf16x4*>(dst)[j] = o;
}

// ---------------------------------------------------------------------------
// Generic batched bf16 MFMA GEMM: C[m,n] = sum_k A[m*lda+k] * B[n*ldb+k]
// 128x128 tile (4 waves 2x2 of 64x64), BK=64, 16x16x32 mfma.
// global_load_lds staging, XOR-swizzled [128][64] LDS tiles (conflict-free).
// ---------------------------------------------------------------------------
template <typename OutT>
__global__ __launch_bounds__(256) void gemm_bt_kernel(
    const bf16_t* __restrict__ A, const bf16_t* __restrict__ B,
    OutT* __restrict__ C, int Ntot, int K, int lda, int ldb,
    size_t sA, size_t sB, size_t sC)
{
    __shared__ __align__(16) bf16_t As[128 * 64];
    __shared__ __align__(16) bf16_t Bs[128 * 64];

    A += (size_t)blockIdx.z * sA;
    B += (size_t)blockIdx.z * sB;
    C += (size_t)blockIdx.z * sC;

    const int bn = blockIdx.x, bm = blockIdx.y;
    const int tid  = threadIdx.x;
    const int wave = tid >> 6, lane = tid & 63;
    const int lr = lane & 15, q = lane >> 4;
    const int wm = (wave & 1) * 64, wn = (wave >> 1) * 64;

    f32x4 acc[4][4];
    #pragma unroll
    for (int i = 0; i < 4; ++i)
        #pragma unroll
        for (int j = 0; j < 4; ++j)
            acc[i][j] = (f32x4){0.f, 0.f, 0.f, 0.f};

    const int row_a0 = bm * 128, row_b0 = bn * 128;
    const int srow = tid >> 3;
    const int gsw  = (((tid & 7) ^ (srow & 7))) * 8;   // swizzled global chunk
    const int lsl  = (tid & 7) * 8;                    // natural LDS slot

    for (int kt = 0; kt < K; kt += 64) {
        #pragma unroll
        for (int i = 0; i < 4; ++i) {
            int row = srow + i * 32;
            load_lds16(&A[(size_t)(row_a0 + row) * lda + kt + gsw], &As[row * 64 + lsl]);
            load_lds16(&B[(size_t)(row_b0 + row) * ldb + kt + gsw], &Bs[row * 64 + lsl]);
        }
        __syncthreads();
        #pragma unroll
        for (int k0 = 0; k0 < 64; k0 += 32) {
            bf16x8 af[4], bfr[4];
            #pragma unroll
            for (int mi = 0; mi < 4; ++mi) {
                int r = wm + mi * 16 + lr, kc = (k0 >> 3) + q;
                af[mi] = *reinterpret_cast<const bf16x8*>(
                    &As[r * 64 + ((kc ^ (r & 7)) << 3)]);
            }
            #pragma unroll
            for (int ni = 0; ni < 4; ++ni) {
                int r = wn + ni * 16 + lr, kc = (k0 >> 3) + q;
                bfr[ni] = *reinterpret_cast<const bf16x8*>(
                    &Bs[r * 64 + ((kc ^ (r & 7)) << 3)]);
            }
            #pragma unroll
            for (int mi = 0; mi < 4; ++mi)
                #pragma unroll
                for (int ni = 0; ni < 4; ++ni)
                    acc[mi][ni] = __builtin_amdgcn_mfma_f32_16x16x32_bf16(
                        af[mi], bfr[ni], acc[mi][ni], 0, 0, 0);
        }
        __syncthreads();
    }

    #pragma unroll
    for (int mi = 0; mi < 4; ++mi)
        #pragma unroll
        for (int ni = 0; ni < 4; ++ni)
            #pragma unroll
            for (int ri = 0; ri < 4; ++ri) {
                int row = row_a0 + wm + mi * 16 + q * 4 + ri;
                int col = row_b0 + wn + ni * 16 + lr;
                C[(size_t)row * Ntot + col] = (OutT)acc[mi][ni][ri];
            }
}

// ---------------------------------------------------------------------------
// Y-GEMM: Y[i,p] = sum_{k<256} Mx[i,k] * Dx[p,k]; Dx = [Xt | Stb] per chunk.
// Same swizzled staging.
// ---------------------------------------------------------------------------
__global__ __launch_bounds__(256) void gemm_y_kernel(
    const bf16_t* __restrict__ Mx, const bf16_t* __restrict__ Xt,
    const bf16_t* __restrict__ Stb, float* __restrict__ yf)
{
    __shared__ __align__(16) bf16_t As[128 * 64];
    __shared__ __align__(16) bf16_t Bs[128 * 64];

    const int bc = blockIdx.z, bn = blockIdx.x;
    const bf16_t* Ab = Mx + (size_t)bc * 32768;                      // 128x256
    const bf16_t* Xb = Xt  + (size_t)bc * 131072 + (size_t)bn * 128 * 128;
    const bf16_t* Sb = Stb + (size_t)bc * 131072 + (size_t)bn * 128 * 128;
    float* Cb = yf + (size_t)bc * 131072;

    const int tid  = threadIdx.x;
    const int wave = tid >> 6, lane = tid & 63;
    const int lr = lane & 15, q = lane >> 4;
    const int wm = (wave & 1) * 64, wn = (wave >> 1) * 64;

    f32x4 acc[4][4];
    #pragma unroll
    for (int i = 0; i < 4; ++i)
        #pragma unroll
        for (int j = 0; j < 4; ++j)
            acc[i][j] = (f32x4){0.f, 0.f, 0.f, 0.f};

    const int srow = tid >> 3;
    const int gsw  = (((tid & 7) ^ (srow & 7))) * 8;
    const int lsl  = (tid & 7) * 8;

    for (int kt = 0; kt < 256; kt += 64) {
        const bf16_t* bsrc = (kt < 128) ? (Xb + kt) : (Sb + (kt - 128));
        #pragma unroll
        for (int i = 0; i < 4; ++i) {
            int row = srow + i * 32;
            load_lds16(&Ab[(size_t)row * 256 + kt + gsw], &As[row * 64 + lsl]);
            load_lds16(&bsrc[(size_t)row * 128 + gsw], &Bs[row * 64 + lsl]);
        }
        __syncthreads();
        #pragma unroll
        for (int k0 = 0; k0 < 64; k0 += 32) {
            bf16x8 af[4], bfr[4];
            #pragma unroll
            for (int mi = 0; mi < 4; ++mi) {
                int r = wm + mi * 16 + lr, kc = (k0 >> 3) + q;
                af[mi] = *reinterpret_cast<const bf16x8*>(
                    &As[r * 64 + ((kc ^ (r & 7)) << 3)]);
            }
            #pragma unroll
            for (int ni = 0; ni < 4; ++ni) {
                int r = wn + ni * 16 + lr, kc = (k0 >> 3) + q;
                bfr[ni] = *reinterpret_cast<const bf16x8*>(
                    &Bs[r * 64 + ((kc ^ (r & 7)) << 3)]);
            }
            #pragma unroll
            for (int mi = 0; mi < 4; ++mi)
                #pragma unroll
                for (int ni = 0; ni < 4; ++ni)
                    acc[mi][ni] = __builtin_amdgcn_mfma_f32_16x16x32_bf16(
                        af[mi], bfr[ni], acc[mi][ni], 0, 0, 0);
        }
        __syncthreads();
    }

    #pragma unroll
    for (int mi = 0; mi < 4; ++mi)
        #pragma unroll
        for (int ni = 0; ni < 4; ++ni)
            #pragma unroll
            for (int ri = 0; ri < 4; ++ri) {
                int row = wm + mi * 16 + q * 4 + ri;
                int col = bn * 128 + wn + ni * 16 + lr;
                Cb[(size_t)row * 1024 + col] = acc[mi][ni][ri];
            }
}

// ---------------------------------------------------------------------------
// dt column + fused x->bf16 cast.  One wave per row.
// ---------------------------------------------------------------------------
__global__ __launch_bounds__(256) void dt_kernel(
    const float* __restrict__ x, const float* __restrict__ W_in,
    const float* __restrict__ dt_bias, float* __restrict__ dtv,
    bf16_t* __restrict__ xb)
{
    int wave = threadIdx.x >> 6, lane = threadIdx.x & 63;
    int r = blockIdx.x * 4 + wave;
    const float* xr = x + (size_t)r * DMODEL + lane * 8;
    const float* wr = W_in + (size_t)NZX * DMODEL + lane * 8;
    float4 a0 = *reinterpret_cast<const float4*>(xr);
    float4 a1 = *reinterpret_cast<const float4*>(xr + 4);
    float4 b0 = *reinterpret_cast<const float4*>(wr);
    float4 b1 = *reinterpret_cast<const float4*>(wr + 4);

    bf16x8 xo;
    xo[0] = (bf16_t)a0.x; xo[1] = (bf16_t)a0.y; xo[2] = (bf16_t)a0.z; xo[3] = (bf16_t)a0.w;
    xo[4] = (bf16_t)a1.x; xo[5] = (bf16_t)a1.y; xo[6] = (bf16_t)a1.z; xo[7] = (bf16_t)a1.w;
    *reinterpret_cast<bf16x8*>(xb + (size_t)r * DMODEL + lane * 8) = xo;

    float s = a0.x * b0.x + a0.y * b0.y + a0.z * b0.z + a0.w * b0.w
            + a1.x * b1.x + a1.y * b1.y + a1.z * b1.z + a1.w * b1.w;
    #pragma unroll
    for (int m = 32; m >= 1; m >>= 1) s += __shfl_xor(s, m);
    if (lane == 0) {
        float t  = s + dt_bias[0];
        dtv[r] = (t > 20.f) ? t : log1pf(expf(t));
    }
}

// ---------------------------------------------------------------------------
// Per-chunk inclusive cumsum of dt -> decay scalars.
// ---------------------------------------------------------------------------
__global__ __launch_bounds__(128) void cumsum_kernel(
    const float* __restrict__ dtv, const float* __restrict__ A_log,
    float* __restrict__ sarr, float* __restrict__ Pv,
    float* __restrict__ EdTv, float* __restrict__ chp)
{
    __shared__ float w0sum, stot;
    int bc = blockIdx.x, j = threadIdx.x;
    int lane = j & 63;
    int r = bc * CHUNK + j;
    float A = -expf(A_log[0]);
    float dt = dtv[r];
    float s = dt;
    #pragma unroll
    for (int m = 1; m <= 32; m <<= 1) {
        float o = __shfl_up(s, m);
        if (lane >= m) s += o;
    }
    if (j == 63) w0sum = s;
    __syncthreads();
    if (j >= 64) s += w0sum;
    if (j == 127) stot = s;
    __syncthreads();
    float sT = stot;
    sarr[r] = s;
    Pv[r]   = expf(A * s);
    EdTv[r] = expf(A * (sT - s)) * dt;
    if (j == 127) chp[bc] = expf(A * sT);
}

// ---------------------------------------------------------------------------
// Causal depthwise conv1d (width 4) + bias + silu -> bf16 XBC_b[8192][1280]
// ---------------------------------------------------------------------------
__global__ __launch_bounds__(256) void conv_kernel(
    const bf16_t* __restrict__ zx, const float* __restrict__ cw,
    const float* __restrict__ cb, bf16_t* __restrict__ xbc)
{
    int flat = blockIdx.x * 256 + threadIdx.x;
    int c4 = flat % (NCONV / 4);
    int r  = flat / (NCONV / 4);
    int l  = r & (SEQLEN - 1);
    int ch = c4 * 4;

    float4 w0 = *reinterpret_cast<const float4*>(cw + (size_t)(ch + 0) * 4);
    float4 w1 = *reinterpret_cast<const float4*>(cw + (size_t)(ch + 1) * 4);
    float4 w2 = *reinterpret_cast<const float4*>(cw + (size_t)(ch + 2) * 4);
    float4 w3 = *reinterpret_cast<const float4*>(cw + (size_t)(ch + 3) * 4);
    float w0a[4] = {w0.x, w0.y, w0.z, w0.w};
    float w1a[4] = {w1.x, w1.y, w1.z, w1.w};
    float w2a[4] = {w2.x, w2.y, w2.z, w2.w};
    float w3a[4] = {w3.x, w3.y, w3.z, w3.w};

    float4 bias = *reinterpret_cast<const float4*>(cb + ch);
    float a0 = bias.x, a1 = bias.y, a2 = bias.z, a3 = bias.w;

    #pragma unroll
    for (int k = 0; k < 4; ++k) {
        if (l + k >= 3) {
            bf16x4 v = *reinterpret_cast<const bf16x4*>(
                zx + (size_t)(r + k - 3) * NZX + DINNER + ch);
            a0 += w0a[k] * (float)v[0];
            a1 += w1a[k] * (float)v[1];
            a2 += w2a[k] * (float)v[2];
            a3 += w3a[k] * (float)v[3];
        }
    }
    bf16x4 o;
    o[0] = (bf16_t)siluf(a0); o[1] = (bf16_t)siluf(a1);
    o[2] = (bf16_t)siluf(a2); o[3] = (bf16_t)siluf(a3);
    *reinterpret_cast<bf16x4*>(xbc + (size_t)r * NCONV + ch) = o;
}

// ---------------------------------------------------------------------------
// LDS-tiled transpose per (chunk, 128-col group):
//  cg<8:  Xt[bc][p][j]  = XBC_b[bc*128+j][cg*128+p]
//  cg==8: Bwt[bc][n][j] = EdTv[j] * XBC_b[bc*128+j][1024+n]
// ---------------------------------------------------------------------------
__global__ __launch_bounds__(256) void transpose_kernel(
    const bf16_t* __restrict__ xbc, const float* __restrict__ EdTv,
    bf16_t* __restrict__ Xt, bf16_t* __restrict__ Bwt)
{
    constexpr int TS = 132;
    __shared__ bf16_t tile[128 * TS];
    int cg = blockIdx.x, bc = blockIdx.y;
    int tid = threadIdx.x;
    int lrow = tid >> 4, lc8 = (tid & 15) * 8;

    #pragma unroll
    for (int pass = 0; pass < 8; ++pass) {
        int row = pass * 16 + lrow;
        bf16x8 v = *reinterpret_cast<const bf16x8*>(
            xbc + (size_t)(bc * 128 + row) * NCONV + cg * 128 + lc8);
        bf16x4 lo, hi;
        #pragma unroll
        for (int m = 0; m < 4; ++m) { lo[m] = v[m]; hi[m] = v[m + 4]; }
        *reinterpret_cast<bf16x4*>(&tile[row * TS + lc8]) = lo;
        *reinterpret_cast<bf16x4*>(&tile[row * TS + lc8 + 4]) = hi;
    }
    __syncthreads();

    const bool isB = (cg == 8);
    int jo = (tid >> 4) * 8;
    float sc[8];
    #pragma unroll
    for (int m = 0; m < 8; ++m)
        sc[m] = isB ? EdTv[bc * 128 + jo + m] : 1.f;

    #pragma unroll
    for (int pass = 0; pass < 8; ++pass) {
        int oc = pass * 16 + (tid & 15);
        bf16x8 o;
        #pragma unroll
        for (int m = 0; m < 8; ++m)
            o[m] = (bf16_t)((float)tile[(jo + m) * TS + oc] * sc[m]);
        bf16_t* dst = isB
            ? (Bwt + (size_t)bc * 16384 + (size_t)oc * 128 + jo)
            : (Xt + (size_t)bc * 131072 + ((size_t)cg * 128 + oc) * 128 + jo);
        *reinterpret_cast<bf16x8*>(dst) = o;
    }
}

// ---------------------------------------------------------------------------
// Sequential chunk combine: S_init(c) = chp(c-1)*S_init(c-1) + S_loc(c-1)
// ---------------------------------------------------------------------------
__global__ __launch_bounds__(256) void scan_combine_kernel(
    const float* __restrict__ cstate, const float* __restrict__ chp,
    bf16_t* __restrict__ Stb)
{
    int idx = blockIdx.x * 256 + threadIdx.x;   // B * 131072
    int b   = idx >> 17;
    int np  = idx & 131071;
    float v = 0.f;
    for (int c = 0; c < NCHUNK; ++c) {
        size_t off = ((size_t)(b * NCHUNK + c) << 17) + np;
        Stb[off] = (bf16_t)v;
        float tmp = cstate[off];
        v = chp[b * NCHUNK + c] * v + tmp;
    }
}

// ---------------------------------------------------------------------------
// mbuild (fused GEMM-G): per chunk, stage C,B tiles (swizzled), MFMA
// G = C@B^T, then write Mx = [mask-decay(G) | P*C] bf16.
// ---------------------------------------------------------------------------
__global__ __launch_bounds__(256) void mbuild_kernel(
    const float* __restrict__ sarr, const float* __restrict__ dtv,
    const float* __restrict__ Pv, const float* __restrict__ A_log,
    const bf16_t* __restrict__ xbc, bf16_t* __restrict__ Mx)
{
    __shared__ __align__(16) bf16_t Cs[128 * 128];
    __shared__ __align__(16) bf16_t Bs2[128 * 128];
    __shared__ float sj[CHUNK], dj[CHUNK], pj[CHUNK];

    int bc = blockIdx.x, tid = threadIdx.x;
    if (tid < CHUNK) {
        sj[tid] = sarr[bc * CHUNK + tid];
        dj[tid] = dtv[bc * CHUNK + tid];
        pj[tid] = Pv[bc * CHUNK + tid];
    }
    int rowbase = bc * 128;
    int srow = tid >> 4;
    int gsw  = (((tid & 15) ^ (srow & 7))) * 8;   // swizzled global chunk
    int lsl  = (tid & 15) * 8;                    // natural LDS slot
    #pragma unroll
    for (int i = 0; i < 8; ++i) {
        int row = srow + i * 16;
        load_lds16(&xbc[(size_t)(rowbase + row) * NCONV + 1152 + gsw], &Cs[row * 128 + lsl]);
        load_lds16(&xbc[(size_t)(rowbase + row) * NCONV + 1024 + gsw], &Bs2[row * 128 + lsl]);
    }
    __syncthreads();

    const int wave = tid >> 6, lane = tid & 63;
    const int lr = lane & 15, q = lane >> 4;
    const int wm = (wave & 1) * 64, wn = (wave >> 1) * 64;

    f32x4 acc[4][4];
    #pragma unroll
    for (int i = 0; i < 4; ++i)
        #pragma unroll
        for (int j = 0; j < 4; ++j)
            acc[i][j] = (f32x4){0.f, 0.f, 0.f, 0.f};

    #pragma unroll
    for (int k0 = 0; k0 < 128; k0 += 32) {
        bf16x8 af[4], bfr[4];
        #pragma unroll
        for (int mi = 0; mi < 4; ++mi) {
            int r = wm + mi * 16 + lr, kc = (k0 >> 3) + q;
            af[mi] = *reinterpret_cast<const bf16x8*>(
                &Cs[r * 128 + ((kc ^ (r & 7)) << 3)]);
        }
        #pragma unroll
        for (int ni = 0; ni < 4; ++ni) {
            int r = wn + ni * 16 + lr, kc = (k0 >> 3) + q;
            bfr[ni] = *reinterpret_cast<const bf16x8*>(
                &Bs2[r * 128 + ((kc ^ (r & 7)) << 3)]);
        }
        #pragma unroll
        for (int mi = 0; mi < 4; ++mi)
            #pragma unroll
            for (int ni = 0; ni < 4; ++ni)
                acc[mi][ni] = __builtin_amdgcn_mfma_f32_16x16x32_bf16(
                    af[mi], bfr[ni], acc[mi][ni], 0, 0, 0);
    }

    float A = -expf(A_log[0]);
    bf16_t* MxB = Mx + (size_t)bc * 32768;
    #pragma unroll
    for (int mi = 0; mi < 4; ++mi)
        #pragma unroll
        for (int ni = 0; ni < 4; ++ni)
            #pragma unroll
            for (int ri = 0; ri < 4; ++ri) {
                int row = wm + mi * 16 + q * 4 + ri;
                int col = wn + ni * 16 + lr;
                float val = 0.f;
                if (col <= row)
                    val = acc[mi][ni][ri] * expf(A * (sj[row] - sj[col])) * dj[col];
                MxB[(size_t)row * 256 + col] = (bf16_t)val;
            }

    // Cw half from LDS (account for swizzle): Mx[row][128+n] = P_row * C[row][n]
    int rr = tid >> 1, cb2 = (tid & 1) * 64;
    float Pi = pj[rr];
    #pragma unroll
    for (int m0 = 0; m0 < 64; m0 += 8) {
        int kc = (cb2 + m0) >> 3;
        bf16x8 cv = *reinterpret_cast<const bf16x8*>(
            &Cs[rr * 128 + ((kc ^ (rr & 7)) << 3)]);
        bf16x8 o;
        #pragma unroll
        for (int m = 0; m < 8; ++m) o[m] = (bf16_t)((float)cv[m] * Pi);
        *reinterpret_cast<bf16x8*>(&MxB[(size_t)rr * 256 + 128 + cb2 + m0]) = o;
    }
}

// ---------------------------------------------------------------------------
// Gate + RMSNorm: y = yf + D*x; g = y*silu(z); g *= rsqrt(mean g^2+eps)*norm_w
// ---------------------------------------------------------------------------
__global__ __launch_bounds__(256) void gate_norm_kernel(
    const float* __restrict__ yf, const bf16_t* __restrict__ zx,
    const bf16_t* __restrict__ xbc, const float* __restrict__ Dp,
    const float* __restrict__ norm_w, bf16_t* __restrict__ yb)
{
    __shared__ float red[4];
    int r = blockIdx.x, tid = threadIdx.x;
    int p = tid * 4;
    float D0 = Dp[0];
    float4 y = *reinterpret_cast<const float4*>(yf + (size_t)r * DINNER + p);
    bf16x4 zv = *reinterpret_cast<const bf16x4*>(zx + (size_t)r * NZX + p);
    bf16x4 xv = *reinterpret_cast<const bf16x4*>(xbc + (size_t)r * NCONV + p);
    float g0 = (y.x + D0 * (float)xv[0]) * siluf((float)zv[0]);
    float g1 = (y.y + D0 * (float)xv[1]) * siluf((float)zv[1]);
    float g2 = (y.z + D0 * (float)xv[2]) * siluf((float)zv[2]);
    float g3 = (y.w + D0 * (float)xv[3]) * siluf((float)zv[3]);
    float ss = g0 * g0 + g1 * g1 + g2 * g2 + g3 * g3;
    #pragma unroll
    for (int m = 32; m >= 1; m >>= 1) ss += __shfl_xor(ss, m);
    if ((tid & 63) == 0) red[tid >> 6] = ss;
    __syncthreads();
    float tot = red[0] + red[1] + red[2] + red[3];
    float scale = rsqrtf(tot * (1.f / 1024.f) + 1e-5f);
    float4 nw = *reinterpret_cast<const float4*>(norm_w + p);
    bf16x4 o;
    o[0] = (bf16_t)(g0 * scale * nw.x);
    o[1] = (bf16_t)(g1 * scale * nw.y);
    o[2] = (bf16_t)(g2 * scale * nw.z);
    o[3] = (bf16_t)(g3 * scale * nw.w);
    *reinterpret_cast<bf16x4*>(yb + (size_t)r * DINNER + p) = o;
}

// ---------------------------------------------------------------------------
__global__ __launch_bounds__(256) void copy_f32_kernel(
    const float* __restrict__ in, float* __restrict__ out, int n)
{
    int i = blockIdx.x * 256 + threadIdx.x;
    if (i < n) out[i] = in[i];
}

// ---------------------------------------------------------------------------
extern "C" void kernel_launch(void* const* d_in, const int* in_sizes, int n_in,
                              void* d_out, int out_size, void* d_ws, size_t ws_size,
                              hipStream_t stream)
{
    const float* x        = (const float*)d_in[0];
    const float* rnn      = (const float*)d_in[1];
    const float* W_in     = (const float*)d_in[2];
    const float* conv_w   = (const float*)d_in[3];
    const float* conv_b   = (const float*)d_in[4];
    const float* dt_bias  = (const float*)d_in[5];
    const float* A_log    = (const float*)d_in[6];
    const float* Dp       = (const float*)d_in[7];
    const float* norm_w   = (const float*)d_in[8];
    const float* W_out    = (const float*)d_in[9];
    float* out = (float*)d_out;

    // workspace carve
    char* ws = (char*)d_ws;
    bf16_t* xb     = (bf16_t*)(ws + 0);                       //  8,388,608
    bf16_t* Mx     = (bf16_t*)(ws + 4194304);                 //  4,194,304 (alias over xb tail, after GEMM1)
    bf16_t* winb   = (bf16_t*)(ws + 8388608);                 //  2,360,320
    bf16_t* woutb  = (bf16_t*)(ws + 10748928);                //  1,048,576
    bf16_t* zx     = (bf16_t*)(ws + 11797504);                // 37,748,736
    float*  dtv    = (float*) (ws + 49546240);                //     32,768
    float*  sarr   = (float*) (ws + 49579008);                //     32,768
    float*  Pv     = (float*) (ws + 49611776);                //     32,768
    float*  EdTv   = (float*) (ws + 49644544);                //     32,768
    float*  chp    = (float*) (ws + 49677312);                //        256
    bf16_t* xbcb   = (bf16_t*)(ws + 49677568);                // 20,971,520
    bf16_t* Xt     = (bf16_t*)(ws + 70649088);                // 16,777,216
    bf16_t* Bwt    = (bf16_t*)(ws + 87426304);                //  2,097,152
    float*  cstate = (float*) (ws + 89523456);                // 33,554,432 (S_loc)
    float*  yf     = (float*) (ws + 89523456);                // alias over dead cstate
    bf16_t* Stb    = (bf16_t*)(ws + 123077888);               // 16,777,216
    bf16_t* yb     = (bf16_t*)(ws + 139855104);               // 16,777,216
    // end: 156,632,320 bytes

    // 1) dt column (fp32) + fused x->bf16 cast; merged weight casts
    dt_kernel<<<MROWS / 4, 256, 0, stream>>>(x, W_in, dt_bias, dtv, xb);
    {
        int n4a = 2305 * DMODEL / 4, n4b = DMODEL * DINNER / 4;
        cast2_kernel<<<(n4a + n4b + 255) / 256, 256, 0, stream>>>(
            W_in, winb, n4a, W_out, woutb, n4b);
    }
    cumsum_kernel<<<NBC, 128, 0, stream>>>(dtv, A_log, sarr, Pv, EdTv, chp);

    // 2) GEMM1: zx[8192,2304] = xb @ winb^T (bf16 out)
    gemm_bt_kernel<bf16_t><<<dim3(NZX / 128, MROWS / 128, 1), 256, 0, stream>>>(
        xb, winb, zx, NZX, DMODEL, DMODEL, DMODEL, 0, 0, 0);

    // 3) conv + bias + silu -> bf16 XBC_b
    conv_kernel<<<MROWS * (NCONV / 4) / 256, 256, 0, stream>>>(zx, conv_w, conv_b, xbcb);

    // 4) transpose: Xt (x part), Bwt (decay-scaled B part)
    transpose_kernel<<<dim3(9, NBC), 256, 0, stream>>>(xbcb, EdTv, Xt, Bwt);

    // 5) GEMM-A: S_loc[p,n] = Xt @ Bwt^T  (per chunk, fp32 out)
    gemm_bt_kernel<float><<<dim3(1, 8, NBC), 256, 0, stream>>>(
        Xt, Bwt, cstate, DSTATE, CHUNK, CHUNK, CHUNK,
        131072, 16384, 131072);

    // 6) combine -> Stb bf16 (S_init per chunk, [p,n])
    scan_combine_kernel<<<BATCH * 131072 / 256, 256, 0, stream>>>(cstate, chp, Stb);

    // 7) mbuild (fused G-GEMM): Mx = [decay-masked C@B^T | P*C]
    mbuild_kernel<<<NBC, 256, 0, stream>>>(sarr, dtv, Pv, A_log, xbcb, Mx);

    // 8) GEMM-Y: yf[i,p] = Mx @ [Xt;Stb]^T  (scan output, fp32)
    gemm_y_kernel<<<dim3(8, 1, NBC), 256, 0, stream>>>(Mx, Xt, Stb, yf);

    // 9) gate + RMSNorm (+ D*x) -> yb bf16
    gate_norm_kernel<<<MROWS, 256, 0, stream>>>(yf, zx, xbcb, Dp, norm_w, yb);

    // 10) GEMM2: out[8192,512] = yb @ woutb^T (f32, into d_out)
    gemm_bt_kernel<float><<<dim3(DMODEL / 128, MROWS / 128, 1), 256, 0, stream>>>(
        yb, woutb, out, DMODEL, DINNER, DINNER, DINNER, 0, 0, 0);

    // 11) rnn_state passthrough
    copy_f32_kernel<<<(BATCH * DMODEL + 255) / 256, 256, 0, stream>>>(
        rnn, out + (size_t)MROWS * DMODEL, BATCH * DMODEL);
}

// Round 8
// 233.009 us; speedup vs baseline: 6.7172x; 1.0867x over previous
//
#include <hip/hip_runtime.h>
#include <cstdint>
#include <cstddef>

// ---------------------------------------------------------------------------
// Mamba2 layer forward (B=4, L=2048, d_model=512, d_inner=1024, d_state=128,
// nheads=1, d_conv=4). SSD formulation: scan as chunked bf16 MFMA GEMMs.
// R5 SSD rewrite 609->281; R6 global_load_lds 281->263 (but 16-way LDS
// conflicts); R7 XOR-swizzle 263->253. R8: traffic+launch consolidation —
// conv+transpose fused, S_loc/yf in bf16, dt+casts merged, rnn copy fused
// into gate_norm. 10 launches, ~-55MB HBM.
// ---------------------------------------------------------------------------

typedef __bf16 bf16_t;
typedef __bf16 bf16x8 __attribute__((ext_vector_type(8)));
typedef __bf16 bf16x4 __attribute__((ext_vector_type(4)));
typedef float  f32x4  __attribute__((ext_vector_type(4)));

#define BATCH   4
#define SEQLEN  2048
#define MROWS   8192
#define DMODEL  512
#define DINNER  1024
#define DSTATE  128
#define NZX     2304
#define NCONV   1280
#define CHUNK   128
#define NCHUNK  16
#define NBC     64            // BATCH * NCHUNK

__device__ __forceinline__ float siluf(float x) { return x / (1.f + __expf(-x)); }

// async global->LDS, 16B per lane. LDS dst is wave-uniform base + lane*16.
__device__ __forceinline__ void load_lds16(const bf16_t* g, bf16_t* l)
{
    __builtin_amdgcn_global_load_lds(
        (const __attribute__((address_space(1))) void*)g,
        (__attribute__((address_space(3))) void*)l,
        16, 0, 0);
}

// ---------------------------------------------------------------------------
// Generic batched bf16 MFMA GEMM: C[m,n] = sum_k A[m*lda+k] * B[n*ldb+k]
// 128x128 tile (4 waves 2x2 of 64x64), BK=64, 16x16x32 mfma.
// global_load_lds staging, XOR-swizzled [128][64] LDS tiles (2-way = free).
// ---------------------------------------------------------------------------
template <typename OutT>
__global__ __launch_bounds__(256) void gemm_bt_kernel(
    const bf16_t* __restrict__ A, const bf16_t* __restrict__ B,
    OutT* __restrict__ C, int Ntot, int K, int lda, int ldb,
    size_t sA, size_t sB, size_t sC)
{
    __shared__ __align__(16) bf16_t As[128 * 64];
    __shared__ __align__(16) bf16_t Bs[128 * 64];

    A += (size_t)blockIdx.z * sA;
    B += (size_t)blockIdx.z * sB;
    C += (size_t)blockIdx.z * sC;

    const int bn = blockIdx.x, bm = blockIdx.y;
    const int tid  = threadIdx.x;
    const int wave = tid >> 6, lane = tid & 63;
    const int lr = lane & 15, q = lane >> 4;
    const int wm = (wave & 1) * 64, wn = (wave >> 1) * 64;

    f32x4 acc[4][4];
    #pragma unroll
    for (int i = 0; i < 4; ++i)
        #pragma unroll
        for (int j = 0; j < 4; ++j)
            acc[i][j] = (f32x4){0.f, 0.f, 0.f, 0.f};

    const int row_a0 = bm * 128, row_b0 = bn * 128;
    const int srow = tid >> 3;
    const int gsw  = (((tid & 7) ^ (srow & 7))) * 8;   // swizzled global chunk
    const int lsl  = (tid & 7) * 8;                    // natural LDS slot

    for (int kt = 0; kt < K; kt += 64) {
        #pragma unroll
        for (int i = 0; i < 4; ++i) {
            int row = srow + i * 32;
            load_lds16(&A[(size_t)(row_a0 + row) * lda + kt + gsw], &As[row * 64 + lsl]);
            load_lds16(&B[(size_t)(row_b0 + row) * ldb + kt + gsw], &Bs[row * 64 + lsl]);
        }
        __syncthreads();
        #pragma unroll
        for (int k0 = 0; k0 < 64; k0 += 32) {
            bf16x8 af[4], bfr[4];
            #pragma unroll
            for (int mi = 0; mi < 4; ++mi) {
                int r = wm + mi * 16 + lr, kc = (k0 >> 3) + q;
                af[mi] = *reinterpret_cast<const bf16x8*>(
                    &As[r * 64 + ((kc ^ (r & 7)) << 3)]);
            }
            #pragma unroll
            for (int ni = 0; ni < 4; ++ni) {
                int r = wn + ni * 16 + lr, kc = (k0 >> 3) + q;
                bfr[ni] = *reinterpret_cast<const bf16x8*>(
                    &Bs[r * 64 + ((kc ^ (r & 7)) << 3)]);
            }
            #pragma unroll
            for (int mi = 0; mi < 4; ++mi)
                #pragma unroll
                for (int ni = 0; ni < 4; ++ni)
                    acc[mi][ni] = __builtin_amdgcn_mfma_f32_16x16x32_bf16(
                        af[mi], bfr[ni], acc[mi][ni], 0, 0, 0);
        }
        __syncthreads();
    }

    #pragma unroll
    for (int mi = 0; mi < 4; ++mi)
        #pragma unroll
        for (int ni = 0; ni < 4; ++ni)
            #pragma unroll
            for (int ri = 0; ri < 4; ++ri) {
                int row = row_a0 + wm + mi * 16 + q * 4 + ri;
                int col = row_b0 + wn + ni * 16 + lr;
                C[(size_t)row * Ntot + col] = (OutT)acc[mi][ni][ri];
            }
}

// ---------------------------------------------------------------------------
// Y-GEMM: Y[i,p] = sum_{k<256} Mx[i,k] * Dx[p,k]; Dx = [Xt | Stb] per chunk.
// Output bf16.
// ---------------------------------------------------------------------------
__global__ __launch_bounds__(256) void gemm_y_kernel(
    const bf16_t* __restrict__ Mx, const bf16_t* __restrict__ Xt,
    const bf16_t* __restrict__ Stb, bf16_t* __restrict__ yf)
{
    __shared__ __align__(16) bf16_t As[128 * 64];
    __shared__ __align__(16) bf16_t Bs[128 * 64];

    const int bc = blockIdx.z, bn = blockIdx.x;
    const bf16_t* Ab = Mx + (size_t)bc * 32768;                      // 128x256
    const bf16_t* Xb = Xt  + (size_t)bc * 131072 + (size_t)bn * 128 * 128;
    const bf16_t* Sb = Stb + (size_t)bc * 131072 + (size_t)bn * 128 * 128;
    bf16_t* Cb = yf + (size_t)bc * 131072;

    const int tid  = threadIdx.x;
    const int wave = tid >> 6, lane = tid & 63;
    const int lr = lane & 15, q = lane >> 4;
    const int wm = (wave & 1) * 64, wn = (wave >> 1) * 64;

    f32x4 acc[4][4];
    #pragma unroll
    for (int i = 0; i < 4; ++i)
        #pragma unroll
        for (int j = 0; j < 4; ++j)
            acc[i][j] = (f32x4){0.f, 0.f, 0.f, 0.f};

    const int srow = tid >> 3;
    const int gsw  = (((tid & 7) ^ (srow & 7))) * 8;
    const int lsl  = (tid & 7) * 8;

    for (int kt = 0; kt < 256; kt += 64) {
        const bf16_t* bsrc = (kt < 128) ? (Xb + kt) : (Sb + (kt - 128));
        #pragma unroll
        for (int i = 0; i < 4; ++i) {
            int row = srow + i * 32;
            load_lds16(&Ab[(size_t)row * 256 + kt + gsw], &As[row * 64 + lsl]);
            load_lds16(&bsrc[(size_t)row * 128 + gsw], &Bs[row * 64 + lsl]);
        }
        __syncthreads();
        #pragma unroll
        for (int k0 = 0; k0 < 64; k0 += 32) {
            bf16x8 af[4], bfr[4];
            #pragma unroll
            for (int mi = 0; mi < 4; ++mi) {
                int r = wm + mi * 16 + lr, kc = (k0 >> 3) + q;
                af[mi] = *reinterpret_cast<const bf16x8*>(
                    &As[r * 64 + ((kc ^ (r & 7)) << 3)]);
            }
            #pragma unroll
            for (int ni = 0; ni < 4; ++ni) {
                int r = wn + ni * 16 + lr, kc = (k0 >> 3) + q;
                bfr[ni] = *reinterpret_cast<const bf16x8*>(
                    &Bs[r * 64 + ((kc ^ (r & 7)) << 3)]);
            }
            #pragma unroll
            for (int mi = 0; mi < 4; ++mi)
                #pragma unroll
                for (int ni = 0; ni < 4; ++ni)
                    acc[mi][ni] = __builtin_amdgcn_mfma_f32_16x16x32_bf16(
                        af[mi], bfr[ni], acc[mi][ni], 0, 0, 0);
        }
        __syncthreads();
    }

    #pragma unroll
    for (int mi = 0; mi < 4; ++mi)
        #pragma unroll
        for (int ni = 0; ni < 4; ++ni)
            #pragma unroll
            for (int ri = 0; ri < 4; ++ri) {
                int row = wm + mi * 16 + q * 4 + ri;
                int col = bn * 128 + wn + ni * 16 + lr;
                Cb[(size_t)row * 1024 + col] = (bf16_t)acc[mi][ni][ri];
            }
}

// ---------------------------------------------------------------------------
// Fused: dt column (one wave per row, fp32 exact) + x->bf16 cast  [blocks
// 0..2047], then W_in/W_out -> bf16 casts [blocks 2048..].
// ---------------------------------------------------------------------------
__global__ __launch_bounds__(256) void dtcast_kernel(
    const float* __restrict__ x, const float* __restrict__ W_in,
    const float* __restrict__ dt_bias, const float* __restrict__ W_out,
    float* __restrict__ dtv, bf16_t* __restrict__ xb,
    bf16_t* __restrict__ winb, bf16_t* __restrict__ woutb)
{
    int bid = blockIdx.x;
    if (bid < MROWS / 4) {
        int wave = threadIdx.x >> 6, lane = threadIdx.x & 63;
        int r = bid * 4 + wave;
        const float* xr = x + (size_t)r * DMODEL + lane * 8;
        const float* wr = W_in + (size_t)NZX * DMODEL + lane * 8;
        float4 a0 = *reinterpret_cast<const float4*>(xr);
        float4 a1 = *reinterpret_cast<const float4*>(xr + 4);
        float4 b0 = *reinterpret_cast<const float4*>(wr);
        float4 b1 = *reinterpret_cast<const float4*>(wr + 4);

        bf16x8 xo;
        xo[0] = (bf16_t)a0.x; xo[1] = (bf16_t)a0.y; xo[2] = (bf16_t)a0.z; xo[3] = (bf16_t)a0.w;
        xo[4] = (bf16_t)a1.x; xo[5] = (bf16_t)a1.y; xo[6] = (bf16_t)a1.z; xo[7] = (bf16_t)a1.w;
        *reinterpret_cast<bf16x8*>(xb + (size_t)r * DMODEL + lane * 8) = xo;

        float s = a0.x * b0.x + a0.y * b0.y + a0.z * b0.z + a0.w * b0.w
                + a1.x * b1.x + a1.y * b1.y + a1.z * b1.z + a1.w * b1.w;
        #pragma unroll
        for (int m = 32; m >= 1; m >>= 1) s += __shfl_xor(s, m);
        if (lane == 0) {
            float t  = s + dt_bias[0];
            dtv[r] = (t > 20.f) ? t : log1pf(expf(t));
        }
        return;
    }
    int i = (bid - MROWS / 4) * 256 + threadIdx.x;
    const int n4a = 2305 * DMODEL / 4, n4b = DMODEL * DINNER / 4;
    const float* src; bf16_t* dst; int j;
    if (i < n4a)            { src = W_in;  dst = winb;  j = i; }
    else if (i < n4a + n4b) { src = W_out; dst = woutb; j = i - n4a; }
    else return;
    float4 v = reinterpret_cast<const float4*>(src)[j];
    bf16x4 o;
    o[0] = (bf16_t)v.x; o[1] = (bf16_t)v.y; o[2] = (bf16_t)v.z; o[3] = (bf16_t)v.w;
    reinterpret_cast<bf16x4*>(dst)[j] = o;
}

// ---------------------------------------------------------------------------
// Per-chunk inclusive cumsum of dt -> decay scalars.
// ---------------------------------------------------------------------------
__global__ __launch_bounds__(128) void cumsum_kernel(
    const float* __restrict__ dtv, const float* __restrict__ A_log,
    float* __restrict__ sarr, float* __restrict__ Pv,
    float* __restrict__ EdTv, float* __restrict__ chp)
{
    __shared__ float w0sum, stot;
    int bc = blockIdx.x, j = threadIdx.x;
    int lane = j & 63;
    int r = bc * CHUNK + j;
    float A = -expf(A_log[0]);
    float dt = dtv[r];
    float s = dt;
    #pragma unroll
    for (int m = 1; m <= 32; m <<= 1) {
        float o = __shfl_up(s, m);
        if (lane >= m) s += o;
    }
    if (j == 63) w0sum = s;
    __syncthreads();
    if (j >= 64) s += w0sum;
    if (j == 127) stot = s;
    __syncthreads();
    float sT = stot;
    sarr[r] = s;
    Pv[r]   = expf(A * s);
    EdTv[r] = expf(A * (sT - s)) * dt;
    if (j == 127) chp[bc] = expf(A * sT);
}

// ---------------------------------------------------------------------------
// Fused conv + transpose per (col-group cg 0..9, chunk bc).
//   conv: xbc[g][c0+c] = silu(bias + sum_k w*zx[g+k-3][1024+c0+c]) (bf16 out)
//   cg<8:  also Xt[bc][c0+oc][j] = xbc[bc*128+j][c0+oc]
//   cg==8: also Bwt[bc][oc][j] = EdTv[j]*xbc[...][1024+oc]
//   cg==9: conv only (C columns, used row-major downstream)
// ---------------------------------------------------------------------------
__global__ __launch_bounds__(256) void conv_tr_kernel(
    const bf16_t* __restrict__ zx, const float* __restrict__ cw,
    const float* __restrict__ cb, const float* __restrict__ EdTv,
    bf16_t* __restrict__ xbc, bf16_t* __restrict__ Xt, bf16_t* __restrict__ Bwt)
{
    constexpr int TS = 132;
    __shared__ bf16_t tile[128 * TS];
    __shared__ float cwS[128 * 4];
    __shared__ float cbS[128];

    int cg = blockIdx.x, bc = blockIdx.y;
    int tid = threadIdx.x;
    int c0 = cg * 128;

    if (tid < 128) {
        float4 w = *reinterpret_cast<const float4*>(cw + (size_t)(c0 + tid) * 4);
        *reinterpret_cast<float4*>(&cwS[tid * 4]) = w;
        cbS[tid] = cb[c0 + tid];
    }
    __syncthreads();

    int lrow = tid >> 4, lc8 = (tid & 15) * 8;
    int g0 = bc * 128;

    #pragma unroll
    for (int pass = 0; pass < 8; ++pass) {
        int row = pass * 16 + lrow;
        int g = g0 + row;
        int l = g & (SEQLEN - 1);
        float acc[8];
        #pragma unroll
        for (int m = 0; m < 8; ++m) acc[m] = cbS[lc8 + m];
        #pragma unroll
        for (int k = 0; k < 4; ++k) {
            if (l + k >= 3) {
                bf16x8 v = *reinterpret_cast<const bf16x8*>(
                    zx + (size_t)(g + k - 3) * NZX + DINNER + c0 + lc8);
                #pragma unroll
                for (int m = 0; m < 8; ++m)
                    acc[m] += cwS[(lc8 + m) * 4 + k] * (float)v[m];
            }
        }
        bf16x8 o;
        #pragma unroll
        for (int m = 0; m < 8; ++m) o[m] = (bf16_t)siluf(acc[m]);
        *reinterpret_cast<bf16x8*>(xbc + (size_t)g * NCONV + c0 + lc8) = o;
        if (cg < 9) {
            bf16x4 lo, hi;
            #pragma unroll
            for (int m = 0; m < 4; ++m) { lo[m] = o[m]; hi[m] = o[m + 4]; }
            *reinterpret_cast<bf16x4*>(&tile[row * TS + lc8]) = lo;
            *reinterpret_cast<bf16x4*>(&tile[row * TS + lc8 + 4]) = hi;
        }
    }
    if (cg == 9) return;
    __syncthreads();

    const bool isB = (cg == 8);
    int jo = (tid >> 4) * 8;
    float sc[8];
    #pragma unroll
    for (int m = 0; m < 8; ++m)
        sc[m] = isB ? EdTv[bc * 128 + jo + m] : 1.f;

    #pragma unroll
    for (int pass = 0; pass < 8; ++pass) {
        int oc = pass * 16 + (tid & 15);
        bf16x8 o;
        #pragma unroll
        for (int m = 0; m < 8; ++m)
            o[m] = (bf16_t)((float)tile[(jo + m) * TS + oc] * sc[m]);
        bf16_t* dst = isB
            ? (Bwt + (size_t)bc * 16384 + (size_t)oc * 128 + jo)
            : (Xt + (size_t)bc * 131072 + ((size_t)c0 + oc) * 128 + jo);
        *reinterpret_cast<bf16x8*>(dst) = o;
    }
}

// ---------------------------------------------------------------------------
// Sequential chunk combine: S_init(c) = chp(c-1)*S_init(c-1) + S_loc(c-1)
// S_loc read as bf16; accumulation fp32; S_init written bf16 (exclusive).
// ---------------------------------------------------------------------------
__global__ __launch_bounds__(256) void scan_combine_kernel(
    const bf16_t* __restrict__ cstate, const float* __restrict__ chp,
    bf16_t* __restrict__ Stb)
{
    int idx = blockIdx.x * 256 + threadIdx.x;   // B * 131072
    int b   = idx >> 17;
    int np  = idx & 131071;
    float v = 0.f;
    for (int c = 0; c < NCHUNK; ++c) {
        size_t off = ((size_t)(b * NCHUNK + c) << 17) + np;
        Stb[off] = (bf16_t)v;
        float tmp = (float)cstate[off];
        v = chp[b * NCHUNK + c] * v + tmp;
    }
}

// ---------------------------------------------------------------------------
// mbuild (fused GEMM-G): per chunk, stage C,B tiles (swizzled), MFMA
// G = C@B^T, then write Mx = [mask-decay(G) | P*C] bf16.
// ---------------------------------------------------------------------------
__global__ __launch_bounds__(256) void mbuild_kernel(
    const float* __restrict__ sarr, const float* __restrict__ dtv,
    const float* __restrict__ Pv, const float* __restrict__ A_log,
    const bf16_t* __restrict__ xbc, bf16_t* __restrict__ Mx)
{
    __shared__ __align__(16) bf16_t Cs[128 * 128];
    __shared__ __align__(16) bf16_t Bs2[128 * 128];
    __shared__ float sj[CHUNK], dj[CHUNK], pj[CHUNK];

    int bc = blockIdx.x, tid = threadIdx.x;
    if (tid < CHUNK) {
        sj[tid] = sarr[bc * CHUNK + tid];
        dj[tid] = dtv[bc * CHUNK + tid];
        pj[tid] = Pv[bc * CHUNK + tid];
    }
    int rowbase = bc * 128;
    int srow = tid >> 4;
    int gsw  = (((tid & 15) ^ (srow & 7))) * 8;   // swizzled global chunk
    int lsl  = (tid & 15) * 8;                    // natural LDS slot
    #pragma unroll
    for (int i = 0; i < 8; ++i) {
        int row = srow + i * 16;
        load_lds16(&xbc[(size_t)(rowbase + row) * NCONV + 1152 + gsw], &Cs[row * 128 + lsl]);
        load_lds16(&xbc[(size_t)(rowbase + row) * NCONV + 1024 + gsw], &Bs2[row * 128 + lsl]);
    }
    __syncthreads();

    const int wave = tid >> 6, lane = tid & 63;
    const int lr = lane & 15, q = lane >> 4;
    const int wm = (wave & 1) * 64, wn = (wave >> 1) * 64;

    f32x4 acc[4][4];
    #pragma unroll
    for (int i = 0; i < 4; ++i)
        #pragma unroll
        for (int j = 0; j < 4; ++j)
            acc[i][j] = (f32x4){0.f, 0.f, 0.f, 0.f};

    #pragma unroll
    for (int k0 = 0; k0 < 128; k0 += 32) {
        bf16x8 af[4], bfr[4];
        #pragma unroll
        for (int mi = 0; mi < 4; ++mi) {
            int r = wm + mi * 16 + lr, kc = (k0 >> 3) + q;
            af[mi] = *reinterpret_cast<const bf16x8*>(
                &Cs[r * 128 + ((kc ^ (r & 7)) << 3)]);
        }
        #pragma unroll
        for (int ni = 0; ni < 4; ++ni) {
            int r = wn + ni * 16 + lr, kc = (k0 >> 3) + q;
            bfr[ni] = *reinterpret_cast<const bf16x8*>(
                &Bs2[r * 128 + ((kc ^ (r & 7)) << 3)]);
        }
        #pragma unroll
        for (int mi = 0; mi < 4; ++mi)
            #pragma unroll
            for (int ni = 0; ni < 4; ++ni)
                acc[mi][ni] = __builtin_amdgcn_mfma_f32_16x16x32_bf16(
                    af[mi], bfr[ni], acc[mi][ni], 0, 0, 0);
    }

    float A = -expf(A_log[0]);
    bf16_t* MxB = Mx + (size_t)bc * 32768;
    #pragma unroll
    for (int mi = 0; mi < 4; ++mi)
        #pragma unroll
        for (int ni = 0; ni < 4; ++ni)
            #pragma unroll
            for (int ri = 0; ri < 4; ++ri) {
                int row = wm + mi * 16 + q * 4 + ri;
                int col = wn + ni * 16 + lr;
                float val = 0.f;
                if (col <= row)
                    val = acc[mi][ni][ri] * expf(A * (sj[row] - sj[col])) * dj[col];
                MxB[(size_t)row * 256 + col] = (bf16_t)val;
            }

    // Cw half from LDS (undo swizzle): Mx[row][128+n] = P_row * C[row][n]
    int rr = tid >> 1, cb2 = (tid & 1) * 64;
    float Pi = pj[rr];
    #pragma unroll
    for (int m0 = 0; m0 < 64; m0 += 8) {
        int kc = (cb2 + m0) >> 3;
        bf16x8 cv = *reinterpret_cast<const bf16x8*>(
            &Cs[rr * 128 + ((kc ^ (rr & 7)) << 3)]);
        bf16x8 o;
        #pragma unroll
        for (int m = 0; m < 8; ++m) o[m] = (bf16_t)((float)cv[m] * Pi);
        *reinterpret_cast<bf16x8*>(&MxB[(size_t)rr * 256 + 128 + cb2 + m0]) = o;
    }
}

// ---------------------------------------------------------------------------
// Gate + RMSNorm (+ fused rnn passthrough in tail blocks):
// y = yf + D*x; g = y*silu(z); g *= rsqrt(mean g^2+eps)*norm_w -> bf16
// ---------------------------------------------------------------------------
__global__ __launch_bounds__(256) void gate_norm_kernel(
    const bf16_t* __restrict__ yf, const bf16_t* __restrict__ zx,
    const bf16_t* __restrict__ xbc, const float* __restrict__ Dp,
    const float* __restrict__ norm_w, bf16_t* __restrict__ yb,
    const float* __restrict__ rnn, float* __restrict__ outTail)
{
    __shared__ float red[4];
    int r = blockIdx.x, tid = threadIdx.x;
    if (r >= MROWS) {
        int i = (r - MROWS) * 256 + tid;
        if (i < BATCH * DMODEL) outTail[i] = rnn[i];
        return;
    }
    int p = tid * 4;
    float D0 = Dp[0];
    bf16x4 yv = *reinterpret_cast<const bf16x4*>(yf + (size_t)r * DINNER + p);
    bf16x4 zv = *reinterpret_cast<const bf16x4*>(zx + (size_t)r * NZX + p);
    bf16x4 xv = *reinterpret_cast<const bf16x4*>(xbc + (size_t)r * NCONV + p);
    float g0 = ((float)yv[0] + D0 * (float)xv[0]) * siluf((float)zv[0]);
    float g1 = ((float)yv[1] + D0 * (float)xv[1]) * siluf((float)zv[1]);
    float g2 = ((float)yv[2] + D0 * (float)xv[2]) * siluf((float)zv[2]);
    float g3 = ((float)yv[3] + D0 * (float)xv[3]) * siluf((float)zv[3]);
    float ss = g0 * g0 + g1 * g1 + g2 * g2 + g3 * g3;
    #pragma unroll
    for (int m = 32; m >= 1; m >>= 1) ss += __shfl_xor(ss, m);
    if ((tid & 63) == 0) red[tid >> 6] = ss;
    __syncthreads();
    float tot = red[0] + red[1] + red[2] + red[3];
    float scale = rsqrtf(tot * (1.f / 1024.f) + 1e-5f);
    float4 nw = *reinterpret_cast<const float4*>(norm_w + p);
    bf16x4 o;
    o[0] = (bf16_t)(g0 * scale * nw.x);
    o[1] = (bf16_t)(g1 * scale * nw.y);
    o[2] = (bf16_t)(g2 * scale * nw.z);
    o[3] = (bf16_t)(g3 * scale * nw.w);
    *reinterpret_cast<bf16x4*>(yb + (size_t)r * DINNER + p) = o;
}

// ---------------------------------------------------------------------------
extern "C" void kernel_launch(void* const* d_in, const int* in_sizes, int n_in,
                              void* d_out, int out_size, void* d_ws, size_t ws_size,
                              hipStream_t stream)
{
    const float* x        = (const float*)d_in[0];
    const float* rnn      = (const float*)d_in[1];
    const float* W_in     = (const float*)d_in[2];
    const float* conv_w   = (const float*)d_in[3];
    const float* conv_b   = (const float*)d_in[4];
    const float* dt_bias  = (const float*)d_in[5];
    const float* A_log    = (const float*)d_in[6];
    const float* Dp       = (const float*)d_in[7];
    const float* norm_w   = (const float*)d_in[8];
    const float* W_out    = (const float*)d_in[9];
    float* out = (float*)d_out;

    // workspace carve
    char* ws = (char*)d_ws;
    bf16_t* xb     = (bf16_t*)(ws + 0);                       //  8,388,608 (dead after GEMM1)
    bf16_t* Mx     = (bf16_t*)(ws + 4194304);                 //  4,194,304 (alias over xb tail)
    bf16_t* winb   = (bf16_t*)(ws + 8388608);                 //  2,360,320
    bf16_t* woutb  = (bf16_t*)(ws + 10748928);                //  1,048,576
    bf16_t* zx     = (bf16_t*)(ws + 11797504);                // 37,748,736
    float*  dtv    = (float*) (ws + 49546240);                //     32,768
    float*  sarr   = (float*) (ws + 49579008);                //     32,768
    float*  Pv     = (float*) (ws + 49611776);                //     32,768
    float*  EdTv   = (float*) (ws + 49644544);                //     32,768
    float*  chp    = (float*) (ws + 49677312);                //        256
    bf16_t* xbcb   = (bf16_t*)(ws + 49677568);                // 20,971,520
    bf16_t* Xt     = (bf16_t*)(ws + 70649088);                // 16,777,216
    bf16_t* Bwt    = (bf16_t*)(ws + 87426304);                //  2,097,152
    bf16_t* cstate = (bf16_t*)(ws + 89523456);                // 16,777,216 (S_loc bf16)
    bf16_t* yf     = (bf16_t*)(ws + 89523456);                // alias over dead cstate
    bf16_t* Stb    = (bf16_t*)(ws + 106300672);               // 16,777,216
    bf16_t* yb     = (bf16_t*)(ws + 123077888);               // 16,777,216
    // end: 139,855,104 bytes

    // 1) dt (fp32) + x cast + weight casts (one kernel, block-range split)
    {
        const int n4a = 2305 * DMODEL / 4, n4b = DMODEL * DINNER / 4;
        int grid = MROWS / 4 + (n4a + n4b + 255) / 256;
        dtcast_kernel<<<grid, 256, 0, stream>>>(
            x, W_in, dt_bias, W_out, dtv, xb, winb, woutb);
    }
    cumsum_kernel<<<NBC, 128, 0, stream>>>(dtv, A_log, sarr, Pv, EdTv, chp);

    // 2) GEMM1: zx[8192,2304] = xb @ winb^T (bf16 out)
    gemm_bt_kernel<bf16_t><<<dim3(NZX / 128, MROWS / 128, 1), 256, 0, stream>>>(
        xb, winb, zx, NZX, DMODEL, DMODEL, DMODEL, 0, 0, 0);

    // 3) fused conv + transpose (writes xbcb, Xt, Bwt)
    conv_tr_kernel<<<dim3(10, NBC), 256, 0, stream>>>(
        zx, conv_w, conv_b, EdTv, xbcb, Xt, Bwt);

    // 4) GEMM-A: S_loc[p,n] = Xt @ Bwt^T  (per chunk, bf16 out)
    gemm_bt_kernel<bf16_t><<<dim3(1, 8, NBC), 256, 0, stream>>>(
        Xt, Bwt, cstate, DSTATE, CHUNK, CHUNK, CHUNK,
        131072, 16384, 131072);

    // 5) combine -> Stb bf16 (S_init per chunk, [p,n])
    scan_combine_kernel<<<BATCH * 131072 / 256, 256, 0, stream>>>(cstate, chp, Stb);

    // 6) mbuild (fused G-GEMM): Mx = [decay-masked C@B^T | P*C]
    mbuild_kernel<<<NBC, 256, 0, stream>>>(sarr, dtv, Pv, A_log, xbcb, Mx);

    // 7) GEMM-Y: yf[i,p] = Mx @ [Xt;Stb]^T  (bf16 out)
    gemm_y_kernel<<<dim3(8, 1, NBC), 256, 0, stream>>>(Mx, Xt, Stb, yf);

    // 8) gate + RMSNorm -> yb bf16 (+ rnn passthrough tail blocks)
    gate_norm_kernel<<<MROWS + 8, 256, 0, stream>>>(
        yf, zx, xbcb, Dp, norm_w, yb, rnn, out + (size_t)MROWS * DMODEL);

    // 9) GEMM2: out[8192,512] = yb @ woutb^T (f32, into d_out)
    gemm_bt_kernel<float><<<dim3(DMODEL / 128, MROWS / 128, 1), 256, 0, stream>>>(
        yb, woutb, out, DMODEL, DINNER, DINNER, DINNER, 0, 0, 0);
}